// Round 1
// 265.012 us; speedup vs baseline: 1.0579x; 1.0579x over previous
//
#include <hip/hip_runtime.h>
#include <math.h>

#define Cc 256
#define NH 8
#define HD 32
#define Tt 256
#define MH 256
#define TBL 961  // 31*31 distinct relative offsets

typedef _Float16 f16;
typedef f16 f16x4 __attribute__((ext_vector_type(4)));
typedef f16 f16x8 __attribute__((ext_vector_type(8)));
typedef float f32x4 __attribute__((ext_vector_type(4)));

// stride-32 f16 rows, 16B-chunk XOR swizzle, key=(row>>2)&3.
__device__ __forceinline__ f16x8 ld8(const f16* base, int row, int kc) {
  return *(const f16x8*)&base[row * 32 + ((kc ^ ((row >> 2) & 3)) << 3)];
}
__device__ __forceinline__ void st8(f16* base, int row, int kc, f16x8 v) {
  *(f16x8*)&base[row * 32 + ((kc ^ ((row >> 2) & 3)) << 3)] = v;
}
__device__ __forceinline__ int sidx(int row, int col) {
  return row * 32 + (((col >> 3) ^ ((row >> 2) & 3)) << 3) + (col & 7);
}
// Vt: [d=32][t=256] stride 256, full 3-bit XOR: chunk ^= (d&7).
__device__ __forceinline__ int vsidx(int d, int t) {
  return d * 256 + (((t >> 3) ^ (d & 7)) << 3) + (t & 7);
}
__device__ __forceinline__ f16x8 vld8(const f16* base, int d, int tch) {
  return *(const f16x8*)&base[d * 256 + ((tch ^ (d & 7)) << 3)];
}

// ---------------------------------------------------------------------------
// Kernel 1: prep.  Blocks 0..7: bias-MLP table for one head each.
// Blocks 8..39: convert w_proj fp32 -> fp16.
// ---------------------------------------------------------------------------
__global__ __launch_bounds__(256) void prep_kernel(
    const float* __restrict__ mw1, const float* __restrict__ mb1,
    const float* __restrict__ mw2, const float* __restrict__ mb2,
    const float* __restrict__ w_proj, float* __restrict__ table,
    float* __restrict__ tablemax, f16* __restrict__ wpf) {
  int blk = blockIdx.x, tid = threadIdx.x;
  if (blk >= NH) {
    int base = (blk - NH) * 2048 + tid * 8;
    f16x8 v;
#pragma unroll
    for (int u = 0; u < 8; u++) v[u] = (f16)w_proj[base + u];
    *(f16x8*)&wpf[base] = v;
    return;
  }
  __shared__ float s_w1a[MH], s_w1b[MH], s_b1[MH], s_w2[MH];
  __shared__ float red[256];
  for (int i = tid; i < MH; i += 256) {
    s_w1a[i] = mw1[2 * i];
    s_w1b[i] = mw1[2 * i + 1];
    s_b1[i] = mb1[i];
    s_w2[i] = mw2[blk * MH + i];
  }
  __syncthreads();
  float lmax = -1e30f;
  float b2 = mb2[blk];
  for (int idx = tid; idx < TBL; idx += 256) {
    float fdi = (float)(idx / 31 - 15);
    float fdj = (float)(idx % 31 - 15);
    float d0 = (fdi > 0.f ? 1.f : (fdi < 0.f ? -1.f : 0.f)) * log1pf(fabsf(fdi));
    float d1 = (fdj > 0.f ? 1.f : (fdj < 0.f ? -1.f : 0.f)) * log1pf(fabsf(fdj));
    float o = b2;
    for (int m = 0; m < MH; m++) {
      float hid = fmaxf(fmaf(d0, s_w1a[m], fmaf(d1, s_w1b[m], s_b1[m])), 0.f);
      o = fmaf(hid, s_w2[m], o);
    }
    table[blk * TBL + idx] = o;
    lmax = fmaxf(lmax, o);
  }
  red[tid] = lmax;
  __syncthreads();
  for (int s = 128; s > 0; s >>= 1) {
    if (tid < s) red[tid] = fmaxf(red[tid], red[tid + s]);
    __syncthreads();
  }
  if (tid == 0) tablemax[blk] = red[0];
}

// ---------------------------------------------------------------------------
// Kernel 2: fused QKV + cosine-sim attention, swapped-operand phase 2.
// Block = (b,h), 512 thr = 8 waves.  LDS 68352 B -> 2 blocks/CU.
// R5 lesson: do NOT set launch_bounds min-waves above what the accumulator
// footprint allows (spill -> 3x HBM traffic).  (512,4): 128-reg budget.
// R6 (this round): chunked XCD swizzle.  bh = (o%8)*256 + o/8 puts the 8
// head-blocks sharing x[b] temporally adjacent on ONE XCD (per-XCD working
// set 8 b-slabs = 2 MB <= 4 MB L2; w_qkv 768 KB L2-resident).  Theory:
// phase-1 staging is HBM-load-latency-bound (~900 cy); L2 hits (~200 cy)
// shorten the serial stage->sync->mfma chain.  Predict FETCH 264->~110 MB.
// ---------------------------------------------------------------------------
__global__ __launch_bounds__(512, 4) void fused_attn(
    const float* __restrict__ x, const float* __restrict__ w_qkv,
    const float* __restrict__ b_qkv, const float* __restrict__ table,
    const float* __restrict__ tablemax, const float* __restrict__ tau,
    f16* __restrict__ attnH) {
  __shared__ __align__(16) char smem[68352];
  f16* Qa = (f16*)smem;                    // 16384 B  (ph1: Xa; ph2: P w0..6)
  f16* Ka = (f16*)(smem + 16384);          // 16384 B  (ph1: Wa in first 6 KB)
  f16* Vt = (f16*)(smem + 32768);          // 16384 B
  f16* Pspare = (f16*)(smem + 49152);      // 2304 B   (wave 7's P)
  float* tbv = (float*)(smem + 51456);     // 31x32 float4 = 15872 B
  float* rs = (float*)(smem + 67328);      // 8x32 f32 = 1024 B
  f16* Xa = (f16*)smem;
  f16* Wa = (f16*)(smem + 16384);

  int tid = threadIdx.x;
  int o = blockIdx.x;
  int bh = ((o & 7) << 8) | (o >> 3);  // chunked XCD swizzle (grid 2048 % 8 == 0)
  int b = bh >> 3, h = bh & 7;
  int wv = tid >> 6, ln = tid & 63, lq = ln >> 4, lm = ln & 15;

  const float LOG2E = 1.4426950408889634f;
  float rtau = 1.0f / fmaxf(tau[h], 0.01f);
  float tmaxh = tablemax[h];

  // tbv[di][c] = float4{ tb(c), tb(c-1), tb(c-2), tb(c-3) }, log2-domain,
  // pre-shifted.  Lane reads component r at dj = c0l - r.
  for (int idx = tid; idx < 31 * 32; idx += 512) {
    int di_ = idx >> 5, c = idx & 31;
    float4 v;
    float* vp = (float*)&v;
#pragma unroll
    for (int u = 0; u < 4; u++) {
      int dj = c - u;
      dj = dj < 0 ? 0 : (dj > 30 ? 30 : dj);
      vp[u] = (table[h * TBL + di_ * 31 + dj] - tmaxh - rtau * 1.0001f) * LOG2E;
    }
    *(float4*)&tbv[idx * 4] = v;
  }

  float bj[6];
#pragma unroll
  for (int nt = 0; nt < 6; nt++) {
    int n = nt * 16 + lm;
    int row = ((n >> 5) << 8) + (h << 5) + (n & 31);
    bj[nt] = b_qkv[row];
  }

  // ---- Phase 1: QKV GEMM, M=256 N=96 K=256, MFMA 16x16x32_f16
  f32x4 acc[2][6] = {};
  for (int c0 = 0; c0 < Cc; c0 += 32) {
    {
      int t = tid & 255, cg = tid >> 8;
      f16x8 v0, v1;
#pragma unroll
      for (int cc = 0; cc < 8; cc++)
        v0[cc] = (f16)x[(size_t)b * 65536 + (size_t)(c0 + cg * 16 + cc) * 256 + t];
#pragma unroll
      for (int cc = 0; cc < 8; cc++)
        v1[cc] = (f16)x[(size_t)b * 65536 + (size_t)(c0 + cg * 16 + 8 + cc) * 256 + t];
      st8(Xa, t, cg * 2 + 0, v0);
      st8(Xa, t, cg * 2 + 1, v1);
    }
    if (tid < 384) {
      int n = tid >> 2, ck = tid & 3;
      int row = ((n >> 5) << 8) + (h << 5) + (n & 31);
      const float* wp = w_qkv + (size_t)row * Cc + c0 + ck * 8;
      f16x8 v;
#pragma unroll
      for (int u = 0; u < 8; u++) v[u] = (f16)wp[u];
      st8(Wa, n, ck, v);
    }
    __syncthreads();
    f16x8 af[2], bf[6];
#pragma unroll
    for (int e = 0; e < 2; e++) af[e] = ld8(Xa, wv * 32 + e * 16 + lm, lq);
#pragma unroll
    for (int nt = 0; nt < 6; nt++) bf[nt] = ld8(Wa, nt * 16 + lm, lq);
#pragma unroll
    for (int e = 0; e < 2; e++)
#pragma unroll
      for (int nt = 0; nt < 6; nt++)
        acc[e][nt] = __builtin_amdgcn_mfma_f32_16x16x32_f16(af[e], bf[nt],
                                                            acc[e][nt], 0, 0, 0);
    __syncthreads();
  }

  // epilogue: + bias, scatter to Qa/Ka (t-major) and Vt (d-major)
#pragma unroll
  for (int e = 0; e < 2; e++) {
#pragma unroll
    for (int nt = 0; nt < 6; nt++) {
      int d = (nt & 1) * 16 + lm;
#pragma unroll
      for (int r = 0; r < 4; r++) {
        int t = wv * 32 + e * 16 + lq * 4 + r;
        f16 v = (f16)(acc[e][nt][r] + bj[nt]);
        if (nt < 2)      Qa[sidx(t, d)] = v;
        else if (nt < 4) Ka[sidx(t, d)] = v;
        else             Vt[vsidx(d, t)] = v;
      }
    }
  }
  __syncthreads();

  // normalize Q,K rows in place (fold rtau*log2e into Q)
  if (tid < 256) {
    int t = tid;
    float s = 0.f;
    f16x8 v[4];
#pragma unroll
    for (int ck = 0; ck < 4; ck++) {
      v[ck] = *(f16x8*)&Qa[t * 32 + ck * 8];
#pragma unroll
      for (int u = 0; u < 8; u++) { float f = (float)v[ck][u]; s = fmaf(f, f, s); }
    }
    float sc_ = rsqrtf(s) * rtau * LOG2E;
#pragma unroll
    for (int ck = 0; ck < 4; ck++) {
      f16x8 o2;
#pragma unroll
      for (int u = 0; u < 8; u++) o2[u] = (f16)((float)v[ck][u] * sc_);
      *(f16x8*)&Qa[t * 32 + ck * 8] = o2;
    }
  } else {
    int t = tid - 256;
    float s = 0.f;
    f16x8 v[4];
#pragma unroll
    for (int ck = 0; ck < 4; ck++) {
      v[ck] = *(f16x8*)&Ka[t * 32 + ck * 8];
#pragma unroll
      for (int u = 0; u < 8; u++) { float f = (float)v[ck][u]; s = fmaf(f, f, s); }
    }
    float sc_ = rsqrtf(s);
#pragma unroll
    for (int ck = 0; ck < 4; ck++) {
      f16x8 o2;
#pragma unroll
      for (int u = 0; u < 8; u++) o2[u] = (f16)((float)v[ck][u] * sc_);
      *(f16x8*)&Ka[t * 32 + ck * 8] = o2;
    }
  }
  __syncthreads();

  // hoist Q fragments (B-operand rows q = wv*32+e*16+lm), then Qa -> P space
  f16x8 qf[2];
#pragma unroll
  for (int e = 0; e < 2; e++) qf[e] = ld8(Qa, wv * 32 + e * 16 + lm, lq);
  __syncthreads();  // all waves done reading Qa before it becomes P

  f16* Pme = (wv < 7) ? (Qa + wv * 1152) : Pspare;  // 32 rows x stride 36 f16
  int c0l = lm - lq * 4 + 15;                        // lane-constant dj base
  const float4* tbp = (const float4*)tbv;
  float lsum[2] = {0.f, 0.f};
  f32x4 acco[2][2] = {};
  int dibase = wv * 2 + 15;

  // ---- Phase 2: S^T = mfma(K,Q) -> packed b64 P writes -> PV. No barriers.
  for (int n0 = 0; n0 < Tt; n0 += 32) {
    f16x8 kf[2];
#pragma unroll
    for (int nt = 0; nt < 2; nt++) kf[nt] = ld8(Ka, n0 + nt * 16 + lm, lq);
    f32x4 zero = {0.f, 0.f, 0.f, 0.f};
    f32x4 sc[2][2];
#pragma unroll
    for (int e = 0; e < 2; e++)
#pragma unroll
      for (int nt = 0; nt < 2; nt++)
        sc[e][nt] = __builtin_amdgcn_mfma_f32_16x16x32_f16(kf[nt], qf[e], zero,
                                                           0, 0, 0);
#pragma unroll
    for (int e = 0; e < 2; e++) {
#pragma unroll
      for (int nt = 0; nt < 2; nt++) {
        int di_ = dibase + e - (n0 >> 4) - nt;
        float4 bv = tbp[di_ * 32 + c0l];
        const float* bvp = (const float*)&bv;
        f16x4 pv;
#pragma unroll
        for (int r = 0; r < 4; r++) {
          float p = exp2f(sc[e][nt][r] + bvp[r]);
          lsum[e] += p;
          pv[r] = (f16)p;
        }
        *(f16x4*)&Pme[(e * 16 + lm) * 36 + nt * 16 + lq * 4] = pv;
      }
    }
    asm volatile("s_waitcnt lgkmcnt(0)" ::: "memory");
    f16x8 pf[2], vf[2];
#pragma unroll
    for (int e = 0; e < 2; e++) {
      f16x4 p0 = *(f16x4*)&Pme[(e * 16 + lm) * 36 + lq * 8];
      f16x4 p1 = *(f16x4*)&Pme[(e * 16 + lm) * 36 + lq * 8 + 4];
      pf[e] = __builtin_shufflevector(p0, p1, 0, 1, 2, 3, 4, 5, 6, 7);
    }
#pragma unroll
    for (int dt = 0; dt < 2; dt++)
      vf[dt] = vld8(Vt, dt * 16 + lm, (n0 >> 3) + lq);
#pragma unroll
    for (int e = 0; e < 2; e++)
#pragma unroll
      for (int dt = 0; dt < 2; dt++)
        acco[e][dt] = __builtin_amdgcn_mfma_f32_16x16x32_f16(pf[e], vf[dt],
                                                             acco[e][dt], 0, 0, 0);
  }

  // lsum lives at lane lm per (e); reduce over lq lanes, redistribute via LDS
#pragma unroll
  for (int e = 0; e < 2; e++) {
    float v = lsum[e];
    v += __shfl_xor(v, 16);
    v += __shfl_xor(v, 32);
    lsum[e] = v;
  }
  if (ln < 16) {
    rs[wv * 32 + lm] = lsum[0];
    rs[wv * 32 + 16 + lm] = lsum[1];
  }
  asm volatile("s_waitcnt lgkmcnt(0)" ::: "memory");
#pragma unroll
  for (int e = 0; e < 2; e++)
#pragma unroll
    for (int r = 0; r < 4; r++) {
      float rl = __builtin_amdgcn_rcpf(rs[wv * 32 + e * 16 + lq * 4 + r]);
      int q = wv * 32 + e * 16 + lq * 4 + r;
#pragma unroll
      for (int dt = 0; dt < 2; dt++) {
        int d = dt * 16 + lm;
        attnH[((size_t)b * Tt + q) * Cc + h * HD + d] =
            (f16)(acco[e][dt][r] * rl);
      }
    }
}

// ---------------------------------------------------------------------------
// Kernel 3: MFMA proj GEMM, coalesced staging.  A fp16 [B*T][256] x Wf fp16
// [256][256] -> out[b][c][t].  K-step 64 (128B row segments), stride-72 LDS,
// 37.4 KB -> 4 blocks/CU.
// ---------------------------------------------------------------------------
__global__ __launch_bounds__(256, 4) void proj_gemm(
    const f16* __restrict__ A, const f16* __restrict__ wf,
    const float* __restrict__ bp, float* __restrict__ out) {
  __shared__ __align__(16) f16 Af[128 * 72];   // 18432 B
  __shared__ __align__(16) f16 Wsh[128 * 72];  // 18432 B
  __shared__ float sB[128];
  int tid = threadIdx.x;
  int row0 = blockIdx.x * 128;
  int n0g = blockIdx.y * 128;
  int b = row0 >> 8, t0 = row0 & 255;
  int wv = tid >> 6, ln = tid & 63, lq = ln >> 4, lm = ln & 15;
  int cw = (wv & 1) * 64, tw = (wv >> 1) * 64;

  if (tid < 128) sB[tid] = bp[n0g + tid];

  f32x4 acc[4][4] = {};
  for (int k0 = 0; k0 < Cc; k0 += 64) {
#pragma unroll
    for (int p = 0; p < 4; p++) {
      int idx = p * 256 + tid;
      int row = idx >> 3, ch = idx & 7;
      f16x8 v = *(const f16x8*)&A[(size_t)(row0 + row) * Cc + k0 + ch * 8];
      *(f16x8*)&Af[row * 72 + ch * 8] = v;
    }
#pragma unroll
    for (int p = 0; p < 4; p++) {
      int idx = p * 256 + tid;
      int row = idx >> 3, ch = idx & 7;
      f16x8 v = *(const f16x8*)&wf[(size_t)(n0g + row) * Cc + k0 + ch * 8];
      *(f16x8*)&Wsh[row * 72 + ch * 8] = v;
    }
    __syncthreads();
#pragma unroll
    for (int kk = 0; kk < 2; kk++) {
      f16x8 wfr[4], af[4];
#pragma unroll
      for (int i = 0; i < 4; i++)
        wfr[i] = *(f16x8*)&Wsh[(cw + i * 16 + lm) * 72 + (kk * 4 + lq) * 8];
#pragma unroll
      for (int j = 0; j < 4; j++)
        af[j] = *(f16x8*)&Af[(tw + j * 16 + lm) * 72 + (kk * 4 + lq) * 8];
#pragma unroll
      for (int i = 0; i < 4; i++)
#pragma unroll
        for (int j = 0; j < 4; j++)
          acc[i][j] = __builtin_amdgcn_mfma_f32_16x16x32_f16(wfr[i], af[j],
                                                             acc[i][j], 0, 0, 0);
    }
    __syncthreads();
  }

  // epilogue: D[c][t], col = t -> coalesced stores
#pragma unroll
  for (int i = 0; i < 4; i++)
#pragma unroll
    for (int r = 0; r < 4; r++) {
      int crl = cw + i * 16 + lq * 4 + r;
      float bias = sB[crl];
#pragma unroll
      for (int j = 0; j < 4; j++) {
        int tcl = tw + j * 16 + lm;
        out[(size_t)b * 65536 + (size_t)(n0g + crl) * 256 + t0 + tcl] =
            acc[i][j][r] + bias;
      }
    }
}

// ---------------------------------------------------------------------------
extern "C" void kernel_launch(void* const* d_in, const int* in_sizes, int n_in,
                              void* d_out, int out_size, void* d_ws,
                              size_t ws_size, hipStream_t stream) {
  const float* x = (const float*)d_in[0];
  const float* w_qkv = (const float*)d_in[1];
  const float* b_qkv = (const float*)d_in[2];
  const float* w_proj = (const float*)d_in[3];
  const float* b_proj = (const float*)d_in[4];
  const float* mw1 = (const float*)d_in[5];
  const float* mb1 = (const float*)d_in[6];
  const float* mw2 = (const float*)d_in[7];
  const float* mb2 = (const float*)d_in[8];
  const float* tau = (const float*)d_in[9];
  float* out = (float*)d_out;

  const size_t NEEDED = (size_t)(TBL * NH + NH) * 4 + (size_t)65536 * 2 +
                        (size_t)256 * NH * Tt * HD * 2;
  if (ws_size < NEEDED) return;

  float* table = (float*)d_ws;
  float* tablemax = table + TBL * NH;
  f16* wpf = (f16*)(tablemax + NH);
  f16* attnH = wpf + 65536;

  prep_kernel<<<40, 256, 0, stream>>>(mw1, mb1, mw2, mb2, w_proj, table,
                                      tablemax, wpf);
  fused_attn<<<256 * NH, 512, 0, stream>>>(x, w_qkv, b_qkv, table, tablemax,
                                           tau, attnH);
  dim3 g3(512, 2);
  proj_gemm<<<g3, 256, 0, stream>>>(attnH, wpf, b_proj, out);
}

// Round 2
// 257.156 us; speedup vs baseline: 1.0902x; 1.0306x over previous
//
#include <hip/hip_runtime.h>
#include <math.h>

#define Cc 256
#define NH 8
#define HD 32
#define Tt 256
#define MH 256
#define TBL 961  // 31*31 distinct relative offsets

typedef _Float16 f16;
typedef f16 f16x4 __attribute__((ext_vector_type(4)));
typedef f16 f16x8 __attribute__((ext_vector_type(8)));
typedef float f32x4 __attribute__((ext_vector_type(4)));

// stride-32 f16 rows, 16B-chunk XOR swizzle, key=(row>>2)&3.
__device__ __forceinline__ f16x8 ld8(const f16* base, int row, int kc) {
  return *(const f16x8*)&base[row * 32 + ((kc ^ ((row >> 2) & 3)) << 3)];
}
__device__ __forceinline__ void st8(f16* base, int row, int kc, f16x8 v) {
  *(f16x8*)&base[row * 32 + ((kc ^ ((row >> 2) & 3)) << 3)] = v;
}
__device__ __forceinline__ int sidx(int row, int col) {
  return row * 32 + (((col >> 3) ^ ((row >> 2) & 3)) << 3) + (col & 7);
}
// Vt: [d=32][t=256] stride 256, full 3-bit XOR: chunk ^= (d&7).
__device__ __forceinline__ int vsidx(int d, int t) {
  return d * 256 + (((t >> 3) ^ (d & 7)) << 3) + (t & 7);
}
__device__ __forceinline__ f16x8 vld8(const f16* base, int d, int tch) {
  return *(const f16x8*)&base[d * 256 + ((tch ^ (d & 7)) << 3)];
}

// ---------------------------------------------------------------------------
// Kernel 1: prep.  Blocks 0..7: bias-MLP table for one head each.
// Blocks 8..39: convert w_proj fp32 -> fp16.
// Blocks 40..63 (R7): gather w_qkv rows -> per-head f16 wqf[h][96][256]
// so fused_attn staging is a pure f16x8 copy (no gather, no cvt).
// ---------------------------------------------------------------------------
__global__ __launch_bounds__(256) void prep_kernel(
    const float* __restrict__ mw1, const float* __restrict__ mb1,
    const float* __restrict__ mw2, const float* __restrict__ mb2,
    const float* __restrict__ w_proj, const float* __restrict__ w_qkv,
    float* __restrict__ table, float* __restrict__ tablemax,
    f16* __restrict__ wpf, f16* __restrict__ wqf) {
  int blk = blockIdx.x, tid = threadIdx.x;
  if (blk >= NH + 32) {  // w_qkv gather+convert: 768 rows x 32 chunks
    int blk2 = blk - NH - 32;  // 0..23
#pragma unroll
    for (int pass = 0; pass < 4; pass++) {
      int chunkid = blk2 * 256 + tid + pass * 6144;
      int row = chunkid >> 5, ck = chunkid & 31;  // row in [0,768)
      int hh = row / 96, n = row % 96;
      int srow = ((n >> 5) << 8) + (hh << 5) + (n & 31);
      const float* wp = w_qkv + (size_t)srow * Cc + ck * 8;
      f16x8 v;
#pragma unroll
      for (int u = 0; u < 8; u++) v[u] = (f16)wp[u];
      *(f16x8*)&wqf[(size_t)row * Cc + ck * 8] = v;
    }
    return;
  }
  if (blk >= NH) {
    int base = (blk - NH) * 2048 + tid * 8;
    f16x8 v;
#pragma unroll
    for (int u = 0; u < 8; u++) v[u] = (f16)w_proj[base + u];
    *(f16x8*)&wpf[base] = v;
    return;
  }
  __shared__ float s_w1a[MH], s_w1b[MH], s_b1[MH], s_w2[MH];
  __shared__ float red[256];
  for (int i = tid; i < MH; i += 256) {
    s_w1a[i] = mw1[2 * i];
    s_w1b[i] = mw1[2 * i + 1];
    s_b1[i] = mb1[i];
    s_w2[i] = mw2[blk * MH + i];
  }
  __syncthreads();
  float lmax = -1e30f;
  float b2 = mb2[blk];
  for (int idx = tid; idx < TBL; idx += 256) {
    float fdi = (float)(idx / 31 - 15);
    float fdj = (float)(idx % 31 - 15);
    float d0 = (fdi > 0.f ? 1.f : (fdi < 0.f ? -1.f : 0.f)) * log1pf(fabsf(fdi));
    float d1 = (fdj > 0.f ? 1.f : (fdj < 0.f ? -1.f : 0.f)) * log1pf(fabsf(fdj));
    float o = b2;
    for (int m = 0; m < MH; m++) {
      float hid = fmaxf(fmaf(d0, s_w1a[m], fmaf(d1, s_w1b[m], s_b1[m])), 0.f);
      o = fmaf(hid, s_w2[m], o);
    }
    table[blk * TBL + idx] = o;
    lmax = fmaxf(lmax, o);
  }
  red[tid] = lmax;
  __syncthreads();
  for (int s = 128; s > 0; s >>= 1) {
    if (tid < s) red[tid] = fmaxf(red[tid], red[tid + s]);
    __syncthreads();
  }
  if (tid == 0) tablemax[blk] = red[0];
}

// ---------------------------------------------------------------------------
// Kernel 1b (R7): transpose+convert x [B][C][T] fp32 -> xt [B][T][C] f16,
// once, instead of 8x per-block scalar gather inside fused_attn.
// 64x64 tiles, LDS [64][72] f16 with 8-chunk XOR swizzle (aligned b128 reads).
// ---------------------------------------------------------------------------
__global__ __launch_bounds__(256) void xpose_kernel(const float* __restrict__ x,
                                                    f16* __restrict__ xt) {
  __shared__ __align__(16) f16 tile[64 * 72];
  int blk = blockIdx.x;
  int b = blk >> 4, ti = (blk >> 2) & 3, tj = blk & 3;
  int tid = threadIdx.x;
  int tl = tid & 63, cg = tid >> 6;
  const float* xb = x + (size_t)b * 65536;
#pragma unroll
  for (int u = 0; u < 16; u++) {
    int cl = cg * 16 + u;
    float v = xb[(size_t)(ti * 64 + cl) * 256 + tj * 64 + tl];
    tile[tl * 72 + (((cl >> 3) ^ (tl & 7)) << 3) + (cl & 7)] = (f16)v;
  }
  __syncthreads();
  f16* xtb = xt + (size_t)b * 65536;
#pragma unroll
  for (int u = 0; u < 2; u++) {
    int chunk = tid * 2 + u;
    int tr = chunk >> 3, ck = chunk & 7;
    f16x8 v = *(const f16x8*)&tile[tr * 72 + ((ck ^ (tr & 7)) << 3)];
    *(f16x8*)&xtb[(size_t)(tj * 64 + tr) * 256 + ti * 64 + ck * 8] = v;
  }
}

// ---------------------------------------------------------------------------
// Kernel 2: fused QKV + cosine-sim attention, swapped-operand phase 2.
// Block = (b,h), 512 thr = 8 waves.  LDS 68352 B -> 2 blocks/CU.
// R6: chunked XCD swizzle (FETCH 264->36 MB).  R7: phase-1 staging reads
// pre-converted f16 xt/wqf (3x b128 loads + 3x b128 LDS stores per thread
// per iter, next-iter regs prefetched under MFMA) -- replaces 24 scalar
// dword loads + 24 cvts.  Theory: kernel is issue/latency-bound, not BW.
// ---------------------------------------------------------------------------
__global__ __launch_bounds__(512, 4) void fused_attn(
    const f16* __restrict__ xt, const f16* __restrict__ wqf,
    const float* __restrict__ b_qkv, const float* __restrict__ table,
    const float* __restrict__ tablemax, const float* __restrict__ tau,
    f16* __restrict__ attnH) {
  __shared__ __align__(16) char smem[68352];
  f16* Qa = (f16*)smem;                    // 16384 B  (ph1: Xa; ph2: P w0..6)
  f16* Ka = (f16*)(smem + 16384);          // 16384 B  (ph1: Wa in first 6 KB)
  f16* Vt = (f16*)(smem + 32768);          // 16384 B
  f16* Pspare = (f16*)(smem + 49152);      // 2304 B   (wave 7's P)
  float* tbv = (float*)(smem + 51456);     // 31x32 float4 = 15872 B
  float* rs = (float*)(smem + 67328);      // 8x32 f32 = 1024 B
  f16* Xa = (f16*)smem;
  f16* Wa = (f16*)(smem + 16384);

  int tid = threadIdx.x;
  int o = blockIdx.x;
  int bh = ((o & 7) << 8) | (o >> 3);  // chunked XCD swizzle (grid 2048 % 8 == 0)
  int b = bh >> 3, h = bh & 7;
  int wv = tid >> 6, ln = tid & 63, lq = ln >> 4, lm = ln & 15;

  const float LOG2E = 1.4426950408889634f;
  float rtau = 1.0f / fmaxf(tau[h], 0.01f);
  float tmaxh = tablemax[h];

  // tbv[di][c] = float4{ tb(c), tb(c-1), tb(c-2), tb(c-3) }, log2-domain,
  // pre-shifted.  Lane reads component r at dj = c0l - r.
  for (int idx = tid; idx < 31 * 32; idx += 512) {
    int di_ = idx >> 5, c = idx & 31;
    float4 v;
    float* vp = (float*)&v;
#pragma unroll
    for (int u = 0; u < 4; u++) {
      int dj = c - u;
      dj = dj < 0 ? 0 : (dj > 30 ? 30 : dj);
      vp[u] = (table[h * TBL + di_ * 31 + dj] - tmaxh - rtau * 1.0001f) * LOG2E;
    }
    *(float4*)&tbv[idx * 4] = v;
  }

  float bj[6];
#pragma unroll
  for (int nt = 0; nt < 6; nt++) {
    int n = nt * 16 + lm;
    int row = ((n >> 5) << 8) + (h << 5) + (n & 31);
    bj[nt] = b_qkv[row];
  }

  // ---- Phase 1: QKV GEMM, M=256 N=96 K=256, MFMA 16x16x32_f16
  const f16* xtb = xt + (size_t)b * 65536;
  const f16* wqh = wqf + (size_t)h * 24576;
  int xt_ = tid >> 1, xkc = (tid & 1) * 2;  // thread's X chunk pair
  int wn = tid >> 2, wck = tid & 3;         // thread's W chunk (tid<384)

  f32x4 acc[2][6] = {};
  f16x8 xv0, xv1, wvv;
  xv0 = *(const f16x8*)&xtb[xt_ * 256 + xkc * 8];
  xv1 = *(const f16x8*)&xtb[xt_ * 256 + xkc * 8 + 8];
  if (tid < 384) wvv = *(const f16x8*)&wqh[wn * 256 + wck * 8];

  for (int c0 = 0; c0 < Cc; c0 += 32) {
    st8(Xa, xt_, xkc, xv0);
    st8(Xa, xt_, xkc + 1, xv1);
    if (tid < 384) st8(Wa, wn, wck, wvv);
    __syncthreads();
    if (c0 + 32 < Cc) {  // prefetch next K-slice under the MFMAs
      xv0 = *(const f16x8*)&xtb[xt_ * 256 + c0 + 32 + xkc * 8];
      xv1 = *(const f16x8*)&xtb[xt_ * 256 + c0 + 32 + xkc * 8 + 8];
      if (tid < 384) wvv = *(const f16x8*)&wqh[wn * 256 + c0 + 32 + wck * 8];
    }
    f16x8 af[2], bf[6];
#pragma unroll
    for (int e = 0; e < 2; e++) af[e] = ld8(Xa, wv * 32 + e * 16 + lm, lq);
#pragma unroll
    for (int nt = 0; nt < 6; nt++) bf[nt] = ld8(Wa, nt * 16 + lm, lq);
#pragma unroll
    for (int e = 0; e < 2; e++)
#pragma unroll
      for (int nt = 0; nt < 6; nt++)
        acc[e][nt] = __builtin_amdgcn_mfma_f32_16x16x32_f16(af[e], bf[nt],
                                                            acc[e][nt], 0, 0, 0);
    __syncthreads();
  }

  // epilogue: + bias, scatter to Qa/Ka (t-major) and Vt (d-major)
#pragma unroll
  for (int e = 0; e < 2; e++) {
#pragma unroll
    for (int nt = 0; nt < 6; nt++) {
      int d = (nt & 1) * 16 + lm;
#pragma unroll
      for (int r = 0; r < 4; r++) {
        int t = wv * 32 + e * 16 + lq * 4 + r;
        f16 v = (f16)(acc[e][nt][r] + bj[nt]);
        if (nt < 2)      Qa[sidx(t, d)] = v;
        else if (nt < 4) Ka[sidx(t, d)] = v;
        else             Vt[vsidx(d, t)] = v;
      }
    }
  }
  __syncthreads();

  // normalize Q,K rows in place (fold rtau*log2e into Q)
  if (tid < 256) {
    int t = tid;
    float s = 0.f;
    f16x8 v[4];
#pragma unroll
    for (int ck = 0; ck < 4; ck++) {
      v[ck] = *(f16x8*)&Qa[t * 32 + ck * 8];
#pragma unroll
      for (int u = 0; u < 8; u++) { float f = (float)v[ck][u]; s = fmaf(f, f, s); }
    }
    float sc_ = rsqrtf(s) * rtau * LOG2E;
#pragma unroll
    for (int ck = 0; ck < 4; ck++) {
      f16x8 o2;
#pragma unroll
      for (int u = 0; u < 8; u++) o2[u] = (f16)((float)v[ck][u] * sc_);
      *(f16x8*)&Qa[t * 32 + ck * 8] = o2;
    }
  } else {
    int t = tid - 256;
    float s = 0.f;
    f16x8 v[4];
#pragma unroll
    for (int ck = 0; ck < 4; ck++) {
      v[ck] = *(f16x8*)&Ka[t * 32 + ck * 8];
#pragma unroll
      for (int u = 0; u < 8; u++) { float f = (float)v[ck][u]; s = fmaf(f, f, s); }
    }
    float sc_ = rsqrtf(s);
#pragma unroll
    for (int ck = 0; ck < 4; ck++) {
      f16x8 o2;
#pragma unroll
      for (int u = 0; u < 8; u++) o2[u] = (f16)((float)v[ck][u] * sc_);
      *(f16x8*)&Ka[t * 32 + ck * 8] = o2;
    }
  }
  __syncthreads();

  // hoist Q fragments (B-operand rows q = wv*32+e*16+lm), then Qa -> P space
  f16x8 qf[2];
#pragma unroll
  for (int e = 0; e < 2; e++) qf[e] = ld8(Qa, wv * 32 + e * 16 + lm, lq);
  __syncthreads();  // all waves done reading Qa before it becomes P

  f16* Pme = (wv < 7) ? (Qa + wv * 1152) : Pspare;  // 32 rows x stride 36 f16
  int c0l = lm - lq * 4 + 15;                        // lane-constant dj base
  const float4* tbp = (const float4*)tbv;
  float lsum[2] = {0.f, 0.f};
  f32x4 acco[2][2] = {};
  int dibase = wv * 2 + 15;

  // ---- Phase 2: S^T = mfma(K,Q) -> packed b64 P writes -> PV. No barriers.
  for (int n0 = 0; n0 < Tt; n0 += 32) {
    f16x8 kf[2];
#pragma unroll
    for (int nt = 0; nt < 2; nt++) kf[nt] = ld8(Ka, n0 + nt * 16 + lm, lq);
    f32x4 zero = {0.f, 0.f, 0.f, 0.f};
    f32x4 sc[2][2];
#pragma unroll
    for (int e = 0; e < 2; e++)
#pragma unroll
      for (int nt = 0; nt < 2; nt++)
        sc[e][nt] = __builtin_amdgcn_mfma_f32_16x16x32_f16(kf[nt], qf[e], zero,
                                                           0, 0, 0);
#pragma unroll
    for (int e = 0; e < 2; e++) {
#pragma unroll
      for (int nt = 0; nt < 2; nt++) {
        int di_ = dibase + e - (n0 >> 4) - nt;
        float4 bv = tbp[di_ * 32 + c0l];
        const float* bvp = (const float*)&bv;
        f16x4 pv;
#pragma unroll
        for (int r = 0; r < 4; r++) {
          float p = exp2f(sc[e][nt][r] + bvp[r]);
          lsum[e] += p;
          pv[r] = (f16)p;
        }
        *(f16x4*)&Pme[(e * 16 + lm) * 36 + nt * 16 + lq * 4] = pv;
      }
    }
    asm volatile("s_waitcnt lgkmcnt(0)" ::: "memory");
    f16x8 pf[2], vf[2];
#pragma unroll
    for (int e = 0; e < 2; e++) {
      f16x4 p0 = *(f16x4*)&Pme[(e * 16 + lm) * 36 + lq * 8];
      f16x4 p1 = *(f16x4*)&Pme[(e * 16 + lm) * 36 + lq * 8 + 4];
      pf[e] = __builtin_shufflevector(p0, p1, 0, 1, 2, 3, 4, 5, 6, 7);
    }
#pragma unroll
    for (int dt = 0; dt < 2; dt++)
      vf[dt] = vld8(Vt, dt * 16 + lm, (n0 >> 3) + lq);
#pragma unroll
    for (int e = 0; e < 2; e++)
#pragma unroll
      for (int dt = 0; dt < 2; dt++)
        acco[e][dt] = __builtin_amdgcn_mfma_f32_16x16x32_f16(pf[e], vf[dt],
                                                             acco[e][dt], 0, 0, 0);
  }

  // lsum lives at lane lm per (e); reduce over lq lanes, redistribute via LDS
#pragma unroll
  for (int e = 0; e < 2; e++) {
    float v = lsum[e];
    v += __shfl_xor(v, 16);
    v += __shfl_xor(v, 32);
    lsum[e] = v;
  }
  if (ln < 16) {
    rs[wv * 32 + lm] = lsum[0];
    rs[wv * 32 + 16 + lm] = lsum[1];
  }
  asm volatile("s_waitcnt lgkmcnt(0)" ::: "memory");
#pragma unroll
  for (int e = 0; e < 2; e++)
#pragma unroll
    for (int r = 0; r < 4; r++) {
      float rl = __builtin_amdgcn_rcpf(rs[wv * 32 + e * 16 + lq * 4 + r]);
      int q = wv * 32 + e * 16 + lq * 4 + r;
#pragma unroll
      for (int dt = 0; dt < 2; dt++) {
        int d = dt * 16 + lm;
        attnH[((size_t)b * Tt + q) * Cc + h * HD + d] =
            (f16)(acco[e][dt][r] * rl);
      }
    }
}

// ---------------------------------------------------------------------------
// Kernel 3: MFMA proj GEMM, coalesced staging.  A fp16 [B*T][256] x Wf fp16
// [256][256] -> out[b][c][t].  K-step 64 (128B row segments), stride-72 LDS,
// 37.4 KB -> 4 blocks/CU.
// ---------------------------------------------------------------------------
__global__ __launch_bounds__(256, 4) void proj_gemm(
    const f16* __restrict__ A, const f16* __restrict__ wf,
    const float* __restrict__ bp, float* __restrict__ out) {
  __shared__ __align__(16) f16 Af[128 * 72];   // 18432 B
  __shared__ __align__(16) f16 Wsh[128 * 72];  // 18432 B
  __shared__ float sB[128];
  int tid = threadIdx.x;
  int row0 = blockIdx.x * 128;
  int n0g = blockIdx.y * 128;
  int b = row0 >> 8, t0 = row0 & 255;
  int wv = tid >> 6, ln = tid & 63, lq = ln >> 4, lm = ln & 15;
  int cw = (wv & 1) * 64, tw = (wv >> 1) * 64;

  if (tid < 128) sB[tid] = bp[n0g + tid];

  f32x4 acc[4][4] = {};
  for (int k0 = 0; k0 < Cc; k0 += 64) {
#pragma unroll
    for (int p = 0; p < 4; p++) {
      int idx = p * 256 + tid;
      int row = idx >> 3, ch = idx & 7;
      f16x8 v = *(const f16x8*)&A[(size_t)(row0 + row) * Cc + k0 + ch * 8];
      *(f16x8*)&Af[row * 72 + ch * 8] = v;
    }
#pragma unroll
    for (int p = 0; p < 4; p++) {
      int idx = p * 256 + tid;
      int row = idx >> 3, ch = idx & 7;
      f16x8 v = *(const f16x8*)&wf[(size_t)(n0g + row) * Cc + k0 + ch * 8];
      *(f16x8*)&Wsh[row * 72 + ch * 8] = v;
    }
    __syncthreads();
#pragma unroll
    for (int kk = 0; kk < 2; kk++) {
      f16x8 wfr[4], af[4];
#pragma unroll
      for (int i = 0; i < 4; i++)
        wfr[i] = *(f16x8*)&Wsh[(cw + i * 16 + lm) * 72 + (kk * 4 + lq) * 8];
#pragma unroll
      for (int j = 0; j < 4; j++)
        af[j] = *(f16x8*)&Af[(tw + j * 16 + lm) * 72 + (kk * 4 + lq) * 8];
#pragma unroll
      for (int i = 0; i < 4; i++)
#pragma unroll
        for (int j = 0; j < 4; j++)
          acc[i][j] = __builtin_amdgcn_mfma_f32_16x16x32_f16(wfr[i], af[j],
                                                             acc[i][j], 0, 0, 0);
    }
    __syncthreads();
  }

  // epilogue: D[c][t], col = t -> coalesced stores
#pragma unroll
  for (int i = 0; i < 4; i++)
#pragma unroll
    for (int r = 0; r < 4; r++) {
      int crl = cw + i * 16 + lq * 4 + r;
      float bias = sB[crl];
#pragma unroll
      for (int j = 0; j < 4; j++) {
        int tcl = tw + j * 16 + lm;
        out[(size_t)b * 65536 + (size_t)(n0g + crl) * 256 + t0 + tcl] =
            acc[i][j][r] + bias;
      }
    }
}

// ---------------------------------------------------------------------------
extern "C" void kernel_launch(void* const* d_in, const int* in_sizes, int n_in,
                              void* d_out, int out_size, void* d_ws,
                              size_t ws_size, hipStream_t stream) {
  const float* x = (const float*)d_in[0];
  const float* w_qkv = (const float*)d_in[1];
  const float* b_qkv = (const float*)d_in[2];
  const float* w_proj = (const float*)d_in[3];
  const float* b_proj = (const float*)d_in[4];
  const float* mw1 = (const float*)d_in[5];
  const float* mb1 = (const float*)d_in[6];
  const float* mw2 = (const float*)d_in[7];
  const float* mb2 = (const float*)d_in[8];
  const float* tau = (const float*)d_in[9];
  float* out = (float*)d_out;

  const size_t NEEDED = (size_t)(TBL * NH + NH) * 4 + (size_t)65536 * 2 +
                        (size_t)256 * NH * Tt * HD * 2;
  if (ws_size < NEEDED) return;

  float* table = (float*)d_ws;
  float* tablemax = table + TBL * NH;
  f16* wpf = (f16*)(tablemax + NH);
  f16* attnH = wpf + 65536;

  // Stash f16 intermediates in d_out (64 MB fp32): xt = 33.5 MB, wqf = 384 KB.
  // proj_gemm fully overwrites d_out afterwards (stream-ordered).
  f16* xt = (f16*)d_out;
  f16* wqf = (f16*)d_out + (size_t)256 * 65536;

  prep_kernel<<<64, 256, 0, stream>>>(mw1, mb1, mw2, mb2, w_proj, w_qkv, table,
                                      tablemax, wpf, wqf);
  xpose_kernel<<<4096, 256, 0, stream>>>(x, xt);
  fused_attn<<<256 * NH, 512, 0, stream>>>(xt, wqf, b_qkv, table, tablemax,
                                           tau, attnH);
  dim3 g3(512, 2);
  proj_gemm<<<g3, 256, 0, stream>>>(attnH, wpf, b_proj, out);
}

// Round 3
// 256.416 us; speedup vs baseline: 1.0934x; 1.0029x over previous
//
#include <hip/hip_runtime.h>
#include <math.h>

#define Cc 256
#define NH 8
#define HD 32
#define Tt 256
#define MH 256
#define TBL 961  // 31*31 distinct relative offsets

typedef _Float16 f16;
typedef f16 f16x4 __attribute__((ext_vector_type(4)));
typedef f16 f16x8 __attribute__((ext_vector_type(8)));
typedef float f32x4 __attribute__((ext_vector_type(4)));

// stride-32 f16 rows, 16B-chunk XOR swizzle, key=(row>>2)&3.
__device__ __forceinline__ f16x8 ld8(const f16* base, int row, int kc) {
  return *(const f16x8*)&base[row * 32 + ((kc ^ ((row >> 2) & 3)) << 3)];
}
__device__ __forceinline__ void st8(f16* base, int row, int kc, f16x8 v) {
  *(f16x8*)&base[row * 32 + ((kc ^ ((row >> 2) & 3)) << 3)] = v;
}
__device__ __forceinline__ int sidx(int row, int col) {
  return row * 32 + (((col >> 3) ^ ((row >> 2) & 3)) << 3) + (col & 7);
}
// Vt: [d=32][t=256] stride 256, full 3-bit XOR: chunk ^= (d&7).
__device__ __forceinline__ int vsidx(int d, int t) {
  return d * 256 + (((t >> 3) ^ (d & 7)) << 3) + (t & 7);
}
__device__ __forceinline__ f16x8 vld8(const f16* base, int d, int tch) {
  return *(const f16x8*)&base[d * 256 + ((tch ^ (d & 7)) << 3)];
}

// ---------------------------------------------------------------------------
// Kernel 1: prep.  Blocks 0..7: bias-MLP table for one head each.
// Blocks 8..39: convert w_proj fp32 -> fp16.
// Blocks 40..63: gather w_qkv rows -> per-head f16 wqf[h][96][256].
// ---------------------------------------------------------------------------
__global__ __launch_bounds__(256) void prep_kernel(
    const float* __restrict__ mw1, const float* __restrict__ mb1,
    const float* __restrict__ mw2, const float* __restrict__ mb2,
    const float* __restrict__ w_proj, const float* __restrict__ w_qkv,
    float* __restrict__ table, float* __restrict__ tablemax,
    f16* __restrict__ wpf, f16* __restrict__ wqf) {
  int blk = blockIdx.x, tid = threadIdx.x;
  if (blk >= NH + 32) {  // w_qkv gather+convert: 768 rows x 32 chunks
    int blk2 = blk - NH - 32;  // 0..23
#pragma unroll
    for (int pass = 0; pass < 4; pass++) {
      int chunkid = blk2 * 256 + tid + pass * 6144;
      int row = chunkid >> 5, ck = chunkid & 31;  // row in [0,768)
      int hh = row / 96, n = row % 96;
      int srow = ((n >> 5) << 8) + (hh << 5) + (n & 31);
      const float* wp = w_qkv + (size_t)srow * Cc + ck * 8;
      f16x8 v;
#pragma unroll
      for (int u = 0; u < 8; u++) v[u] = (f16)wp[u];
      *(f16x8*)&wqf[(size_t)row * Cc + ck * 8] = v;
    }
    return;
  }
  if (blk >= NH) {
    int base = (blk - NH) * 2048 + tid * 8;
    f16x8 v;
#pragma unroll
    for (int u = 0; u < 8; u++) v[u] = (f16)w_proj[base + u];
    *(f16x8*)&wpf[base] = v;
    return;
  }
  __shared__ float s_w1a[MH], s_w1b[MH], s_b1[MH], s_w2[MH];
  __shared__ float red[256];
  for (int i = tid; i < MH; i += 256) {
    s_w1a[i] = mw1[2 * i];
    s_w1b[i] = mw1[2 * i + 1];
    s_b1[i] = mb1[i];
    s_w2[i] = mw2[blk * MH + i];
  }
  __syncthreads();
  float lmax = -1e30f;
  float b2 = mb2[blk];
  for (int idx = tid; idx < TBL; idx += 256) {
    float fdi = (float)(idx / 31 - 15);
    float fdj = (float)(idx % 31 - 15);
    float d0 = (fdi > 0.f ? 1.f : (fdi < 0.f ? -1.f : 0.f)) * log1pf(fabsf(fdi));
    float d1 = (fdj > 0.f ? 1.f : (fdj < 0.f ? -1.f : 0.f)) * log1pf(fabsf(fdj));
    float o = b2;
    for (int m = 0; m < MH; m++) {
      float hid = fmaxf(fmaf(d0, s_w1a[m], fmaf(d1, s_w1b[m], s_b1[m])), 0.f);
      o = fmaf(hid, s_w2[m], o);
    }
    table[blk * TBL + idx] = o;
    lmax = fmaxf(lmax, o);
  }
  red[tid] = lmax;
  __syncthreads();
  for (int s = 128; s > 0; s >>= 1) {
    if (tid < s) red[tid] = fmaxf(red[tid], red[tid + s]);
    __syncthreads();
  }
  if (tid == 0) tablemax[blk] = red[0];
}

// ---------------------------------------------------------------------------
// Kernel 1b: transpose+convert x [B][C][T] fp32 -> xt [B][T][C] f16.
// R8: float4 loads (16B/lane) instead of 16 scalar dword loads -- G13.
// 64x64 tiles, LDS [64][72] f16 with 8-chunk XOR swizzle (aligned b128 reads).
// ---------------------------------------------------------------------------
__global__ __launch_bounds__(256) void xpose_kernel(const float* __restrict__ x,
                                                    f16* __restrict__ xt) {
  __shared__ __align__(16) f16 tile[64 * 72];
  int blk = blockIdx.x;
  int b = blk >> 4, ti = (blk >> 2) & 3, tj = blk & 3;
  int tid = threadIdx.x;
  const float* xb = x + (size_t)b * 65536;
  int t4 = (tid & 15) * 4, cg = tid >> 4;  // 16 float4 per c-row
#pragma unroll
  for (int p = 0; p < 4; p++) {
    int cl = cg + p * 16;
    float4 v = *(const float4*)&xb[(size_t)(ti * 64 + cl) * 256 + tj * 64 + t4];
    const float* vp = (const float*)&v;
#pragma unroll
    for (int u = 0; u < 4; u++) {
      int tl = t4 + u;
      tile[tl * 72 + (((cl >> 3) ^ (tl & 7)) << 3) + (cl & 7)] = (f16)vp[u];
    }
  }
  __syncthreads();
  f16* xtb = xt + (size_t)b * 65536;
#pragma unroll
  for (int u = 0; u < 2; u++) {
    int chunk = tid * 2 + u;
    int tr = chunk >> 3, ck = chunk & 7;
    f16x8 v = *(const f16x8*)&tile[tr * 72 + ((ck ^ (tr & 7)) << 3)];
    *(f16x8*)&xtb[(size_t)(tj * 64 + tr) * 256 + ti * 64 + ck * 8] = v;
  }
}

// ---------------------------------------------------------------------------
// Kernel 2: fused QKV + cosine-sim attention, swapped-operand phase 2.
// Block = (b,h), 512 thr = 8 waves.  LDS 68352 B -> 2 blocks/CU.
// R6: chunked XCD swizzle (FETCH 264->36 MB).  R7: f16 xt/wqf staging
// (153->106 us).  R8: normalize pass uses ld8/st8 (swizzled chunks) to kill
// its 8-way bank conflict (plain chunk reads hit 8 banks only); setprio(1)
// around phase-2 MFMA clusters (waves drift, m191 regime).
// ---------------------------------------------------------------------------
__global__ __launch_bounds__(512, 4) void fused_attn(
    const f16* __restrict__ xt, const f16* __restrict__ wqf,
    const float* __restrict__ b_qkv, const float* __restrict__ table,
    const float* __restrict__ tablemax, const float* __restrict__ tau,
    f16* __restrict__ attnH) {
  __shared__ __align__(16) char smem[68352];
  f16* Qa = (f16*)smem;                    // 16384 B  (ph1: Xa; ph2: P w0..6)
  f16* Ka = (f16*)(smem + 16384);          // 16384 B  (ph1: Wa in first 6 KB)
  f16* Vt = (f16*)(smem + 32768);          // 16384 B
  f16* Pspare = (f16*)(smem + 49152);      // 2304 B   (wave 7's P)
  float* tbv = (float*)(smem + 51456);     // 31x32 float4 = 15872 B
  float* rs = (float*)(smem + 67328);      // 8x32 f32 = 1024 B
  f16* Xa = (f16*)smem;
  f16* Wa = (f16*)(smem + 16384);

  int tid = threadIdx.x;
  int o = blockIdx.x;
  int bh = ((o & 7) << 8) | (o >> 3);  // chunked XCD swizzle (grid 2048 % 8 == 0)
  int b = bh >> 3, h = bh & 7;
  int wv = tid >> 6, ln = tid & 63, lq = ln >> 4, lm = ln & 15;

  const float LOG2E = 1.4426950408889634f;
  float rtau = 1.0f / fmaxf(tau[h], 0.01f);
  float tmaxh = tablemax[h];

  // tbv[di][c] = float4{ tb(c), tb(c-1), tb(c-2), tb(c-3) }, log2-domain,
  // pre-shifted.  Lane reads component r at dj = c0l - r.
  for (int idx = tid; idx < 31 * 32; idx += 512) {
    int di_ = idx >> 5, c = idx & 31;
    float4 v;
    float* vp = (float*)&v;
#pragma unroll
    for (int u = 0; u < 4; u++) {
      int dj = c - u;
      dj = dj < 0 ? 0 : (dj > 30 ? 30 : dj);
      vp[u] = (table[h * TBL + di_ * 31 + dj] - tmaxh - rtau * 1.0001f) * LOG2E;
    }
    *(float4*)&tbv[idx * 4] = v;
  }

  float bj[6];
#pragma unroll
  for (int nt = 0; nt < 6; nt++) {
    int n = nt * 16 + lm;
    int row = ((n >> 5) << 8) + (h << 5) + (n & 31);
    bj[nt] = b_qkv[row];
  }

  // ---- Phase 1: QKV GEMM, M=256 N=96 K=256, MFMA 16x16x32_f16
  const f16* xtb = xt + (size_t)b * 65536;
  const f16* wqh = wqf + (size_t)h * 24576;
  int xt_ = tid >> 1, xkc = (tid & 1) * 2;  // thread's X chunk pair
  int wn = tid >> 2, wck = tid & 3;         // thread's W chunk (tid<384)

  f32x4 acc[2][6] = {};
  f16x8 xv0, xv1, wvv;
  xv0 = *(const f16x8*)&xtb[xt_ * 256 + xkc * 8];
  xv1 = *(const f16x8*)&xtb[xt_ * 256 + xkc * 8 + 8];
  if (tid < 384) wvv = *(const f16x8*)&wqh[wn * 256 + wck * 8];

  for (int c0 = 0; c0 < Cc; c0 += 32) {
    st8(Xa, xt_, xkc, xv0);
    st8(Xa, xt_, xkc + 1, xv1);
    if (tid < 384) st8(Wa, wn, wck, wvv);
    __syncthreads();
    if (c0 + 32 < Cc) {  // prefetch next K-slice under the MFMAs
      xv0 = *(const f16x8*)&xtb[xt_ * 256 + c0 + 32 + xkc * 8];
      xv1 = *(const f16x8*)&xtb[xt_ * 256 + c0 + 32 + xkc * 8 + 8];
      if (tid < 384) wvv = *(const f16x8*)&wqh[wn * 256 + c0 + 32 + wck * 8];
    }
    f16x8 af[2], bf[6];
#pragma unroll
    for (int e = 0; e < 2; e++) af[e] = ld8(Xa, wv * 32 + e * 16 + lm, lq);
#pragma unroll
    for (int nt = 0; nt < 6; nt++) bf[nt] = ld8(Wa, nt * 16 + lm, lq);
#pragma unroll
    for (int e = 0; e < 2; e++)
#pragma unroll
      for (int nt = 0; nt < 6; nt++)
        acc[e][nt] = __builtin_amdgcn_mfma_f32_16x16x32_f16(af[e], bf[nt],
                                                            acc[e][nt], 0, 0, 0);
    __syncthreads();
  }

  // epilogue: + bias, scatter to Qa/Ka (t-major) and Vt (d-major)
#pragma unroll
  for (int e = 0; e < 2; e++) {
#pragma unroll
    for (int nt = 0; nt < 6; nt++) {
      int d = (nt & 1) * 16 + lm;
#pragma unroll
      for (int r = 0; r < 4; r++) {
        int t = wv * 32 + e * 16 + lq * 4 + r;
        f16 v = (f16)(acc[e][nt][r] + bj[nt]);
        if (nt < 2)      Qa[sidx(t, d)] = v;
        else if (nt < 4) Ka[sidx(t, d)] = v;
        else             Vt[vsidx(d, t)] = v;
      }
    }
  }
  __syncthreads();

  // normalize Q,K rows in place (fold rtau*log2e into Q).
  // R8: ld8/st8 (swizzled logical chunks) -- sum over the row is invariant to
  // chunk order; plain indexing had lanes on 8 banks (8-way conflict).
  if (tid < 256) {
    int t = tid;
    float s = 0.f;
    f16x8 v[4];
#pragma unroll
    for (int ck = 0; ck < 4; ck++) {
      v[ck] = ld8(Qa, t, ck);
#pragma unroll
      for (int u = 0; u < 8; u++) { float f = (float)v[ck][u]; s = fmaf(f, f, s); }
    }
    float sc_ = rsqrtf(s) * rtau * LOG2E;
#pragma unroll
    for (int ck = 0; ck < 4; ck++) {
      f16x8 o2;
#pragma unroll
      for (int u = 0; u < 8; u++) o2[u] = (f16)((float)v[ck][u] * sc_);
      st8(Qa, t, ck, o2);
    }
  } else {
    int t = tid - 256;
    float s = 0.f;
    f16x8 v[4];
#pragma unroll
    for (int ck = 0; ck < 4; ck++) {
      v[ck] = ld8(Ka, t, ck);
#pragma unroll
      for (int u = 0; u < 8; u++) { float f = (float)v[ck][u]; s = fmaf(f, f, s); }
    }
    float sc_ = rsqrtf(s);
#pragma unroll
    for (int ck = 0; ck < 4; ck++) {
      f16x8 o2;
#pragma unroll
      for (int u = 0; u < 8; u++) o2[u] = (f16)((float)v[ck][u] * sc_);
      st8(Ka, t, ck, o2);
    }
  }
  __syncthreads();

  // hoist Q fragments (B-operand rows q = wv*32+e*16+lm), then Qa -> P space
  f16x8 qf[2];
#pragma unroll
  for (int e = 0; e < 2; e++) qf[e] = ld8(Qa, wv * 32 + e * 16 + lm, lq);
  __syncthreads();  // all waves done reading Qa before it becomes P

  f16* Pme = (wv < 7) ? (Qa + wv * 1152) : Pspare;  // 32 rows x stride 36 f16
  int c0l = lm - lq * 4 + 15;                        // lane-constant dj base
  const float4* tbp = (const float4*)tbv;
  float lsum[2] = {0.f, 0.f};
  f32x4 acco[2][2] = {};
  int dibase = wv * 2 + 15;

  // ---- Phase 2: S^T = mfma(K,Q) -> packed b64 P writes -> PV. No barriers.
  for (int n0 = 0; n0 < Tt; n0 += 32) {
    f16x8 kf[2];
#pragma unroll
    for (int nt = 0; nt < 2; nt++) kf[nt] = ld8(Ka, n0 + nt * 16 + lm, lq);
    f32x4 zero = {0.f, 0.f, 0.f, 0.f};
    f32x4 sc[2][2];
    __builtin_amdgcn_s_setprio(1);
#pragma unroll
    for (int e = 0; e < 2; e++)
#pragma unroll
      for (int nt = 0; nt < 2; nt++)
        sc[e][nt] = __builtin_amdgcn_mfma_f32_16x16x32_f16(kf[nt], qf[e], zero,
                                                           0, 0, 0);
    __builtin_amdgcn_s_setprio(0);
#pragma unroll
    for (int e = 0; e < 2; e++) {
#pragma unroll
      for (int nt = 0; nt < 2; nt++) {
        int di_ = dibase + e - (n0 >> 4) - nt;
        float4 bv = tbp[di_ * 32 + c0l];
        const float* bvp = (const float*)&bv;
        f16x4 pv;
#pragma unroll
        for (int r = 0; r < 4; r++) {
          float p = exp2f(sc[e][nt][r] + bvp[r]);
          lsum[e] += p;
          pv[r] = (f16)p;
        }
        *(f16x4*)&Pme[(e * 16 + lm) * 36 + nt * 16 + lq * 4] = pv;
      }
    }
    asm volatile("s_waitcnt lgkmcnt(0)" ::: "memory");
    f16x8 pf[2], vf[2];
#pragma unroll
    for (int e = 0; e < 2; e++) {
      f16x4 p0 = *(f16x4*)&Pme[(e * 16 + lm) * 36 + lq * 8];
      f16x4 p1 = *(f16x4*)&Pme[(e * 16 + lm) * 36 + lq * 8 + 4];
      pf[e] = __builtin_shufflevector(p0, p1, 0, 1, 2, 3, 4, 5, 6, 7);
    }
#pragma unroll
    for (int dt = 0; dt < 2; dt++)
      vf[dt] = vld8(Vt, dt * 16 + lm, (n0 >> 3) + lq);
    __builtin_amdgcn_s_setprio(1);
#pragma unroll
    for (int e = 0; e < 2; e++)
#pragma unroll
      for (int dt = 0; dt < 2; dt++)
        acco[e][dt] = __builtin_amdgcn_mfma_f32_16x16x32_f16(pf[e], vf[dt],
                                                             acco[e][dt], 0, 0, 0);
    __builtin_amdgcn_s_setprio(0);
  }

  // lsum lives at lane lm per (e); reduce over lq lanes, redistribute via LDS
#pragma unroll
  for (int e = 0; e < 2; e++) {
    float v = lsum[e];
    v += __shfl_xor(v, 16);
    v += __shfl_xor(v, 32);
    lsum[e] = v;
  }
  if (ln < 16) {
    rs[wv * 32 + lm] = lsum[0];
    rs[wv * 32 + 16 + lm] = lsum[1];
  }
  asm volatile("s_waitcnt lgkmcnt(0)" ::: "memory");
#pragma unroll
  for (int e = 0; e < 2; e++)
#pragma unroll
    for (int r = 0; r < 4; r++) {
      float rl = __builtin_amdgcn_rcpf(rs[wv * 32 + e * 16 + lq * 4 + r]);
      int q = wv * 32 + e * 16 + lq * 4 + r;
#pragma unroll
      for (int dt = 0; dt < 2; dt++) {
        int d = dt * 16 + lm;
        attnH[((size_t)b * Tt + q) * Cc + h * HD + d] =
            (f16)(acco[e][dt][r] * rl);
      }
    }
}

// ---------------------------------------------------------------------------
// Kernel 3: MFMA proj GEMM, coalesced staging.  A fp16 [B*T][256] x Wf fp16
// [256][256] -> out[b][c][t].  K-step 64 (128B row segments), stride-72 LDS,
// 37.4 KB -> 4 blocks/CU.
// ---------------------------------------------------------------------------
__global__ __launch_bounds__(256, 4) void proj_gemm(
    const f16* __restrict__ A, const f16* __restrict__ wf,
    const float* __restrict__ bp, float* __restrict__ out) {
  __shared__ __align__(16) f16 Af[128 * 72];   // 18432 B
  __shared__ __align__(16) f16 Wsh[128 * 72];  // 18432 B
  __shared__ float sB[128];
  int tid = threadIdx.x;
  int row0 = blockIdx.x * 128;
  int n0g = blockIdx.y * 128;
  int b = row0 >> 8, t0 = row0 & 255;
  int wv = tid >> 6, ln = tid & 63, lq = ln >> 4, lm = ln & 15;
  int cw = (wv & 1) * 64, tw = (wv >> 1) * 64;

  if (tid < 128) sB[tid] = bp[n0g + tid];

  f32x4 acc[4][4] = {};
  for (int k0 = 0; k0 < Cc; k0 += 64) {
#pragma unroll
    for (int p = 0; p < 4; p++) {
      int idx = p * 256 + tid;
      int row = idx >> 3, ch = idx & 7;
      f16x8 v = *(const f16x8*)&A[(size_t)(row0 + row) * Cc + k0 + ch * 8];
      *(f16x8*)&Af[row * 72 + ch * 8] = v;
    }
#pragma unroll
    for (int p = 0; p < 4; p++) {
      int idx = p * 256 + tid;
      int row = idx >> 3, ch = idx & 7;
      f16x8 v = *(const f16x8*)&wf[(size_t)(n0g + row) * Cc + k0 + ch * 8];
      *(f16x8*)&Wsh[row * 72 + ch * 8] = v;
    }
    __syncthreads();
#pragma unroll
    for (int kk = 0; kk < 2; kk++) {
      f16x8 wfr[4], af[4];
#pragma unroll
      for (int i = 0; i < 4; i++)
        wfr[i] = *(f16x8*)&Wsh[(cw + i * 16 + lm) * 72 + (kk * 4 + lq) * 8];
#pragma unroll
      for (int j = 0; j < 4; j++)
        af[j] = *(f16x8*)&Af[(tw + j * 16 + lm) * 72 + (kk * 4 + lq) * 8];
#pragma unroll
      for (int i = 0; i < 4; i++)
#pragma unroll
        for (int j = 0; j < 4; j++)
          acc[i][j] = __builtin_amdgcn_mfma_f32_16x16x32_f16(wfr[i], af[j],
                                                             acc[i][j], 0, 0, 0);
    }
    __syncthreads();
  }

  // epilogue: D[c][t], col = t -> coalesced stores
#pragma unroll
  for (int i = 0; i < 4; i++)
#pragma unroll
    for (int r = 0; r < 4; r++) {
      int crl = cw + i * 16 + lq * 4 + r;
      float bias = sB[crl];
#pragma unroll
      for (int j = 0; j < 4; j++) {
        int tcl = tw + j * 16 + lm;
        out[(size_t)b * 65536 + (size_t)(n0g + crl) * 256 + t0 + tcl] =
            acc[i][j][r] + bias;
      }
    }
}

// ---------------------------------------------------------------------------
extern "C" void kernel_launch(void* const* d_in, const int* in_sizes, int n_in,
                              void* d_out, int out_size, void* d_ws,
                              size_t ws_size, hipStream_t stream) {
  const float* x = (const float*)d_in[0];
  const float* w_qkv = (const float*)d_in[1];
  const float* b_qkv = (const float*)d_in[2];
  const float* w_proj = (const float*)d_in[3];
  const float* b_proj = (const float*)d_in[4];
  const float* mw1 = (const float*)d_in[5];
  const float* mb1 = (const float*)d_in[6];
  const float* mw2 = (const float*)d_in[7];
  const float* mb2 = (const float*)d_in[8];
  const float* tau = (const float*)d_in[9];
  float* out = (float*)d_out;

  const size_t NEEDED = (size_t)(TBL * NH + NH) * 4 + (size_t)65536 * 2 +
                        (size_t)256 * NH * Tt * HD * 2;
  if (ws_size < NEEDED) return;

  float* table = (float*)d_ws;
  float* tablemax = table + TBL * NH;
  f16* wpf = (f16*)(tablemax + NH);
  f16* attnH = wpf + 65536;

  // Stash f16 intermediates in d_out (64 MB fp32): xt = 33.5 MB, wqf = 384 KB.
  // proj_gemm fully overwrites d_out afterwards (stream-ordered).
  f16* xt = (f16*)d_out;
  f16* wqf = (f16*)d_out + (size_t)256 * 65536;

  prep_kernel<<<64, 256, 0, stream>>>(mw1, mb1, mw2, mb2, w_proj, w_qkv, table,
                                      tablemax, wpf, wqf);
  xpose_kernel<<<4096, 256, 0, stream>>>(x, xt);
  fused_attn<<<256 * NH, 512, 0, stream>>>(xt, wqf, b_qkv, table, tablemax,
                                           tau, attnH);
  dim3 g3(512, 2);
  proj_gemm<<<g3, 256, 0, stream>>>(attnH, wpf, b_proj, out);
}

// Round 4
// 244.698 us; speedup vs baseline: 1.1457x; 1.0479x over previous
//
#include <hip/hip_runtime.h>
#include <math.h>

#define Cc 256
#define NH 8
#define HD 32
#define Tt 256
#define MH 256
#define TBL 961  // 31*31 distinct relative offsets

typedef _Float16 f16;
typedef f16 f16x4 __attribute__((ext_vector_type(4)));
typedef f16 f16x8 __attribute__((ext_vector_type(8)));
typedef float f32x4 __attribute__((ext_vector_type(4)));

// stride-32 f16 rows, 16B-chunk XOR swizzle, key=(row>>2)&3.
__device__ __forceinline__ f16x8 ld8(const f16* base, int row, int kc) {
  return *(const f16x8*)&base[row * 32 + ((kc ^ ((row >> 2) & 3)) << 3)];
}
__device__ __forceinline__ void st8(f16* base, int row, int kc, f16x8 v) {
  *(f16x8*)&base[row * 32 + ((kc ^ ((row >> 2) & 3)) << 3)] = v;
}
__device__ __forceinline__ int sidx(int row, int col) {
  return row * 32 + (((col >> 3) ^ ((row >> 2) & 3)) << 3) + (col & 7);
}
// Vt: [d=32][t=256] stride 256, full 3-bit XOR: chunk ^= (d&7).
__device__ __forceinline__ int vsidx(int d, int t) {
  return d * 256 + (((t >> 3) ^ (d & 7)) << 3) + (t & 7);
}
__device__ __forceinline__ f16x8 vld8(const f16* base, int d, int tch) {
  return *(const f16x8*)&base[d * 256 + ((tch ^ (d & 7)) << 3)];
}

// ---------------------------------------------------------------------------
// Kernel 1 (R9: merged prep+xpose = stage0, one launch).
// Blocks 0..4095: transpose+convert x [B][C][T] fp32 -> xt [B][T][C] f16.
// Blocks 4096..4103: bias-MLP table (R9: float4-packed weights, 4-entry ILP
//   -- was 4096 wave-uniform scalar ds_reads + a serial 256-long fma chain).
// Blocks 4104..4135: w_proj fp32->f16.  Blocks 4136..4159: w_qkv gather.
// ---------------------------------------------------------------------------
__global__ __launch_bounds__(256) void stage0_kernel(
    const float* __restrict__ x, f16* __restrict__ xt,
    const float* __restrict__ mw1, const float* __restrict__ mb1,
    const float* __restrict__ mw2, const float* __restrict__ mb2,
    const float* __restrict__ w_proj, const float* __restrict__ w_qkv,
    float* __restrict__ table, float* __restrict__ tablemax,
    f16* __restrict__ wpf, f16* __restrict__ wqf) {
  __shared__ __align__(16) char smem0[9216];
  int tid = threadIdx.x;
  int blk = blockIdx.x;

  if (blk < 4096) {  // ---- xpose: 64x64 tile, float4 loads (G13)
    f16* tile = (f16*)smem0;  // [64][72] f16, 8-chunk XOR swizzle
    int b = blk >> 4, ti = (blk >> 2) & 3, tj = blk & 3;
    const float* xb = x + (size_t)b * 65536;
    int t4 = (tid & 15) * 4, cg = tid >> 4;
#pragma unroll
    for (int p = 0; p < 4; p++) {
      int cl = cg + p * 16;
      float4 v = *(const float4*)&xb[(size_t)(ti * 64 + cl) * 256 + tj * 64 + t4];
      const float* vp = (const float*)&v;
#pragma unroll
      for (int u = 0; u < 4; u++) {
        int tl = t4 + u;
        tile[tl * 72 + (((cl >> 3) ^ (tl & 7)) << 3) + (cl & 7)] = (f16)vp[u];
      }
    }
    __syncthreads();
    f16* xtb = xt + (size_t)b * 65536;
#pragma unroll
    for (int u = 0; u < 2; u++) {
      int chunk = tid * 2 + u;
      int tr = chunk >> 3, ck = chunk & 7;
      f16x8 v = *(const f16x8*)&tile[tr * 72 + ((ck ^ (tr & 7)) << 3)];
      *(f16x8*)&xtb[(size_t)(tj * 64 + tr) * 256 + ti * 64 + ck * 8] = v;
    }
    return;
  }

  blk -= 4096;
  if (blk >= NH + 32) {  // ---- w_qkv gather+convert: 768 rows x 32 chunks
    int blk2 = blk - NH - 32;  // 0..23
#pragma unroll
    for (int pass = 0; pass < 4; pass++) {
      int chunkid = blk2 * 256 + tid + pass * 6144;
      int row = chunkid >> 5, ck = chunkid & 31;  // row in [0,768)
      int hh = row / 96, n = row % 96;
      int srow = ((n >> 5) << 8) + (hh << 5) + (n & 31);
      const float* wp = w_qkv + (size_t)srow * Cc + ck * 8;
      f16x8 v;
#pragma unroll
      for (int u = 0; u < 8; u++) v[u] = (f16)wp[u];
      *(f16x8*)&wqf[(size_t)row * Cc + ck * 8] = v;
    }
    return;
  }
  if (blk >= NH) {  // ---- w_proj convert
    int base = (blk - NH) * 2048 + tid * 8;
    f16x8 v;
#pragma unroll
    for (int u = 0; u < 8; u++) v[u] = (f16)w_proj[base + u];
    *(f16x8*)&wpf[base] = v;
    return;
  }
  // ---- bias-MLP table for head `blk`
  float4* s_w = (float4*)smem0;              // [MH] {w1a, w1b, b1, w2}
  float* red = (float*)(smem0 + 4096);       // [256]
  for (int i = tid; i < MH; i += 256) {
    float4 w;
    w.x = mw1[2 * i];
    w.y = mw1[2 * i + 1];
    w.z = mb1[i];
    w.w = mw2[blk * MH + i];
    s_w[i] = w;
  }
  __syncthreads();
  float b2 = mb2[blk];
  float d0v[4], d1v[4], ov[4];
#pragma unroll
  for (int j = 0; j < 4; j++) {
    int idx = tid + j * 256;
    int ii = idx < TBL ? idx : TBL - 1;
    float fdi = (float)(ii / 31 - 15);
    float fdj = (float)(ii % 31 - 15);
    d0v[j] = (fdi > 0.f ? 1.f : (fdi < 0.f ? -1.f : 0.f)) * log1pf(fabsf(fdi));
    d1v[j] = (fdj > 0.f ? 1.f : (fdj < 0.f ? -1.f : 0.f)) * log1pf(fabsf(fdj));
    ov[j] = b2;
  }
  for (int m = 0; m < MH; m++) {
    float4 w = s_w[m];
#pragma unroll
    for (int j = 0; j < 4; j++) {
      float hid = fmaxf(fmaf(d0v[j], w.x, fmaf(d1v[j], w.y, w.z)), 0.f);
      ov[j] = fmaf(hid, w.w, ov[j]);
    }
  }
  float lmax = -1e30f;
#pragma unroll
  for (int j = 0; j < 4; j++) {
    int idx = tid + j * 256;
    if (idx < TBL) {
      table[blk * TBL + idx] = ov[j];
      lmax = fmaxf(lmax, ov[j]);
    }
  }
  red[tid] = lmax;
  __syncthreads();
  for (int s = 128; s > 0; s >>= 1) {
    if (tid < s) red[tid] = fmaxf(red[tid], red[tid + s]);
    __syncthreads();
  }
  if (tid == 0) tablemax[blk] = red[0];
}

// ---------------------------------------------------------------------------
// Kernel 2: fused QKV + cosine-sim attention, swapped-operand phase 2.
// Block = (b,h), 512 thr = 8 waves.  LDS 67328 B -> 2 blocks/CU.
// R6: chunked XCD swizzle.  R7: f16 xt/wqf staging (153->106 us).
// R8: swizzled normalize + setprio (106->92 us).
// R9: (a) softmax denominator via ones-MFMA: mfma(pf[e], ones) accumulated
// over n0 puts sum_n P[q][n] at exactly the lane/reg the epilogue needs --
// deletes 128 v_add_f32 + 2 shuffles + rs LDS roundtrip (VALU 58% is the
// top pipe; MFMA idles at 19%).  (b) V epilogue stores vectorized f16x4
// (t is fast index in Vt rows): 16 scalar 4-way-conflicting b16 -> 4 stores
// at bank floor.
// ---------------------------------------------------------------------------
__global__ __launch_bounds__(512, 4) void fused_attn(
    const f16* __restrict__ xt, const f16* __restrict__ wqf,
    const float* __restrict__ b_qkv, const float* __restrict__ table,
    const float* __restrict__ tablemax, const float* __restrict__ tau,
    f16* __restrict__ attnH) {
  __shared__ __align__(16) char smem[67328];
  f16* Qa = (f16*)smem;                    // 16384 B  (ph1: Xa; ph2: P w0..6)
  f16* Ka = (f16*)(smem + 16384);          // 16384 B  (ph1: Wa in first 6 KB)
  f16* Vt = (f16*)(smem + 32768);          // 16384 B
  f16* Pspare = (f16*)(smem + 49152);      // 2304 B   (wave 7's P)
  float* tbv = (float*)(smem + 51456);     // 31x32 float4 = 15872 B
  f16* Xa = (f16*)smem;
  f16* Wa = (f16*)(smem + 16384);

  int tid = threadIdx.x;
  int o = blockIdx.x;
  int bh = ((o & 7) << 8) | (o >> 3);  // chunked XCD swizzle (grid 2048 % 8 == 0)
  int b = bh >> 3, h = bh & 7;
  int wv = tid >> 6, ln = tid & 63, lq = ln >> 4, lm = ln & 15;

  const float LOG2E = 1.4426950408889634f;
  float rtau = 1.0f / fmaxf(tau[h], 0.01f);
  float tmaxh = tablemax[h];

  // tbv[di][c] = float4{ tb(c), tb(c-1), tb(c-2), tb(c-3) }, log2-domain,
  // pre-shifted.  Lane reads component r at dj = c0l - r.
  for (int idx = tid; idx < 31 * 32; idx += 512) {
    int di_ = idx >> 5, c = idx & 31;
    float4 v;
    float* vp = (float*)&v;
#pragma unroll
    for (int u = 0; u < 4; u++) {
      int dj = c - u;
      dj = dj < 0 ? 0 : (dj > 30 ? 30 : dj);
      vp[u] = (table[h * TBL + di_ * 31 + dj] - tmaxh - rtau * 1.0001f) * LOG2E;
    }
    *(float4*)&tbv[idx * 4] = v;
  }

  float bj[6];
#pragma unroll
  for (int nt = 0; nt < 6; nt++) {
    int n = nt * 16 + lm;
    int row = ((n >> 5) << 8) + (h << 5) + (n & 31);
    bj[nt] = b_qkv[row];
  }

  // ---- Phase 1: QKV GEMM, M=256 N=96 K=256, MFMA 16x16x32_f16
  const f16* xtb = xt + (size_t)b * 65536;
  const f16* wqh = wqf + (size_t)h * 24576;
  int xt_ = tid >> 1, xkc = (tid & 1) * 2;  // thread's X chunk pair
  int wn = tid >> 2, wck = tid & 3;         // thread's W chunk (tid<384)

  f32x4 acc[2][6] = {};
  f16x8 xv0, xv1, wvv;
  xv0 = *(const f16x8*)&xtb[xt_ * 256 + xkc * 8];
  xv1 = *(const f16x8*)&xtb[xt_ * 256 + xkc * 8 + 8];
  if (tid < 384) wvv = *(const f16x8*)&wqh[wn * 256 + wck * 8];

  for (int c0 = 0; c0 < Cc; c0 += 32) {
    st8(Xa, xt_, xkc, xv0);
    st8(Xa, xt_, xkc + 1, xv1);
    if (tid < 384) st8(Wa, wn, wck, wvv);
    __syncthreads();
    if (c0 + 32 < Cc) {  // prefetch next K-slice under the MFMAs
      xv0 = *(const f16x8*)&xtb[xt_ * 256 + c0 + 32 + xkc * 8];
      xv1 = *(const f16x8*)&xtb[xt_ * 256 + c0 + 32 + xkc * 8 + 8];
      if (tid < 384) wvv = *(const f16x8*)&wqh[wn * 256 + c0 + 32 + wck * 8];
    }
    f16x8 af[2], bf[6];
#pragma unroll
    for (int e = 0; e < 2; e++) af[e] = ld8(Xa, wv * 32 + e * 16 + lm, lq);
#pragma unroll
    for (int nt = 0; nt < 6; nt++) bf[nt] = ld8(Wa, nt * 16 + lm, lq);
#pragma unroll
    for (int e = 0; e < 2; e++)
#pragma unroll
      for (int nt = 0; nt < 6; nt++)
        acc[e][nt] = __builtin_amdgcn_mfma_f32_16x16x32_f16(af[e], bf[nt],
                                                            acc[e][nt], 0, 0, 0);
    __syncthreads();
  }

  // epilogue: + bias, scatter to Qa/Ka (t-major, scalar) and Vt (d-major,
  // f16x4: r-index = consecutive t within one swizzle chunk -> bank floor)
#pragma unroll
  for (int e = 0; e < 2; e++) {
#pragma unroll
    for (int nt = 0; nt < 6; nt++) {
      int d = (nt & 1) * 16 + lm;
      if (nt < 4) {
#pragma unroll
        for (int r = 0; r < 4; r++) {
          int t = wv * 32 + e * 16 + lq * 4 + r;
          f16 v = (f16)(acc[e][nt][r] + bj[nt]);
          if (nt < 2) Qa[sidx(t, d)] = v;
          else        Ka[sidx(t, d)] = v;
        }
      } else {
        int t0 = wv * 32 + e * 16 + lq * 4;
        f16x4 pv;
#pragma unroll
        for (int r = 0; r < 4; r++) pv[r] = (f16)(acc[e][nt][r] + bj[nt]);
        *(f16x4*)&Vt[vsidx(d, t0)] = pv;
      }
    }
  }
  __syncthreads();

  // normalize Q,K rows in place (fold rtau*log2e into Q); swizzled chunks
  if (tid < 256) {
    int t = tid;
    float s = 0.f;
    f16x8 v[4];
#pragma unroll
    for (int ck = 0; ck < 4; ck++) {
      v[ck] = ld8(Qa, t, ck);
#pragma unroll
      for (int u = 0; u < 8; u++) { float f = (float)v[ck][u]; s = fmaf(f, f, s); }
    }
    float sc_ = rsqrtf(s) * rtau * LOG2E;
#pragma unroll
    for (int ck = 0; ck < 4; ck++) {
      f16x8 o2;
#pragma unroll
      for (int u = 0; u < 8; u++) o2[u] = (f16)((float)v[ck][u] * sc_);
      st8(Qa, t, ck, o2);
    }
  } else {
    int t = tid - 256;
    float s = 0.f;
    f16x8 v[4];
#pragma unroll
    for (int ck = 0; ck < 4; ck++) {
      v[ck] = ld8(Ka, t, ck);
#pragma unroll
      for (int u = 0; u < 8; u++) { float f = (float)v[ck][u]; s = fmaf(f, f, s); }
    }
    float sc_ = rsqrtf(s);
#pragma unroll
    for (int ck = 0; ck < 4; ck++) {
      f16x8 o2;
#pragma unroll
      for (int u = 0; u < 8; u++) o2[u] = (f16)((float)v[ck][u] * sc_);
      st8(Ka, t, ck, o2);
    }
  }
  __syncthreads();

  // hoist Q fragments (B-operand rows q = wv*32+e*16+lm), then Qa -> P space
  f16x8 qf[2];
#pragma unroll
  for (int e = 0; e < 2; e++) qf[e] = ld8(Qa, wv * 32 + e * 16 + lm, lq);
  __syncthreads();  // all waves done reading Qa before it becomes P

  f16* Pme = (wv < 7) ? (Qa + wv * 1152) : Pspare;  // 32 rows x stride 36 f16
  int c0l = lm - lq * 4 + 15;                        // lane-constant dj base
  const float4* tbp = (const float4*)tbv;
  f32x4 acco[2][2] = {};
  f32x4 acco_s[2] = {};  // ones-MFMA row sums (softmax denominator)
  f16x8 onev;
#pragma unroll
  for (int u = 0; u < 8; u++) onev[u] = (f16)1.0f;
  int dibase = wv * 2 + 15;

  // ---- Phase 2: S^T = mfma(K,Q) -> packed b64 P writes -> PV. No barriers.
  for (int n0 = 0; n0 < Tt; n0 += 32) {
    f16x8 kf[2];
#pragma unroll
    for (int nt = 0; nt < 2; nt++) kf[nt] = ld8(Ka, n0 + nt * 16 + lm, lq);
    f32x4 zero = {0.f, 0.f, 0.f, 0.f};
    f32x4 sc[2][2];
    __builtin_amdgcn_s_setprio(1);
#pragma unroll
    for (int e = 0; e < 2; e++)
#pragma unroll
      for (int nt = 0; nt < 2; nt++)
        sc[e][nt] = __builtin_amdgcn_mfma_f32_16x16x32_f16(kf[nt], qf[e], zero,
                                                           0, 0, 0);
    __builtin_amdgcn_s_setprio(0);
#pragma unroll
    for (int e = 0; e < 2; e++) {
#pragma unroll
      for (int nt = 0; nt < 2; nt++) {
        int di_ = dibase + e - (n0 >> 4) - nt;
        float4 bv = tbp[di_ * 32 + c0l];
        const float* bvp = (const float*)&bv;
        f16x4 pv;
#pragma unroll
        for (int r = 0; r < 4; r++) pv[r] = (f16)exp2f(sc[e][nt][r] + bvp[r]);
        *(f16x4*)&Pme[(e * 16 + lm) * 36 + nt * 16 + lq * 4] = pv;
      }
    }
    asm volatile("s_waitcnt lgkmcnt(0)" ::: "memory");
    f16x8 pf[2], vf[2];
#pragma unroll
    for (int e = 0; e < 2; e++) {
      f16x4 p0 = *(f16x4*)&Pme[(e * 16 + lm) * 36 + lq * 8];
      f16x4 p1 = *(f16x4*)&Pme[(e * 16 + lm) * 36 + lq * 8 + 4];
      pf[e] = __builtin_shufflevector(p0, p1, 0, 1, 2, 3, 4, 5, 6, 7);
    }
#pragma unroll
    for (int dt = 0; dt < 2; dt++)
      vf[dt] = vld8(Vt, dt * 16 + lm, (n0 >> 3) + lq);
    __builtin_amdgcn_s_setprio(1);
#pragma unroll
    for (int e = 0; e < 2; e++) {
#pragma unroll
      for (int dt = 0; dt < 2; dt++)
        acco[e][dt] = __builtin_amdgcn_mfma_f32_16x16x32_f16(pf[e], vf[dt],
                                                             acco[e][dt], 0, 0, 0);
      acco_s[e] = __builtin_amdgcn_mfma_f32_16x16x32_f16(pf[e], onev,
                                                         acco_s[e], 0, 0, 0);
    }
    __builtin_amdgcn_s_setprio(0);
  }

  // acco_s[e][r] = sum_n P[q][n] for q = e*16 + lq*4 + r -- exactly this
  // thread's epilogue rows.  No shuffles, no LDS, no waitcnt.
#pragma unroll
  for (int e = 0; e < 2; e++)
#pragma unroll
    for (int r = 0; r < 4; r++) {
      float rl = __builtin_amdgcn_rcpf(acco_s[e][r]);
      int q = wv * 32 + e * 16 + lq * 4 + r;
#pragma unroll
      for (int dt = 0; dt < 2; dt++) {
        int d = dt * 16 + lm;
        attnH[((size_t)b * Tt + q) * Cc + h * HD + d] =
            (f16)(acco[e][dt][r] * rl);
      }
    }
}

// ---------------------------------------------------------------------------
// Kernel 3: MFMA proj GEMM, coalesced staging.  A fp16 [B*T][256] x Wf fp16
// [256][256] -> out[b][c][t].  K-step 64 (128B row segments), stride-72 LDS,
// 37.4 KB -> 4 blocks/CU.
// ---------------------------------------------------------------------------
__global__ __launch_bounds__(256, 4) void proj_gemm(
    const f16* __restrict__ A, const f16* __restrict__ wf,
    const float* __restrict__ bp, float* __restrict__ out) {
  __shared__ __align__(16) f16 Af[128 * 72];   // 18432 B
  __shared__ __align__(16) f16 Wsh[128 * 72];  // 18432 B
  __shared__ float sB[128];
  int tid = threadIdx.x;
  int row0 = blockIdx.x * 128;
  int n0g = blockIdx.y * 128;
  int b = row0 >> 8, t0 = row0 & 255;
  int wv = tid >> 6, ln = tid & 63, lq = ln >> 4, lm = ln & 15;
  int cw = (wv & 1) * 64, tw = (wv >> 1) * 64;

  if (tid < 128) sB[tid] = bp[n0g + tid];

  f32x4 acc[4][4] = {};
  for (int k0 = 0; k0 < Cc; k0 += 64) {
#pragma unroll
    for (int p = 0; p < 4; p++) {
      int idx = p * 256 + tid;
      int row = idx >> 3, ch = idx & 7;
      f16x8 v = *(const f16x8*)&A[(size_t)(row0 + row) * Cc + k0 + ch * 8];
      *(f16x8*)&Af[row * 72 + ch * 8] = v;
    }
#pragma unroll
    for (int p = 0; p < 4; p++) {
      int idx = p * 256 + tid;
      int row = idx >> 3, ch = idx & 7;
      f16x8 v = *(const f16x8*)&wf[(size_t)(n0g + row) * Cc + k0 + ch * 8];
      *(f16x8*)&Wsh[row * 72 + ch * 8] = v;
    }
    __syncthreads();
#pragma unroll
    for (int kk = 0; kk < 2; kk++) {
      f16x8 wfr[4], af[4];
#pragma unroll
      for (int i = 0; i < 4; i++)
        wfr[i] = *(f16x8*)&Wsh[(cw + i * 16 + lm) * 72 + (kk * 4 + lq) * 8];
#pragma unroll
      for (int j = 0; j < 4; j++)
        af[j] = *(f16x8*)&Af[(tw + j * 16 + lm) * 72 + (kk * 4 + lq) * 8];
#pragma unroll
      for (int i = 0; i < 4; i++)
#pragma unroll
        for (int j = 0; j < 4; j++)
          acc[i][j] = __builtin_amdgcn_mfma_f32_16x16x32_f16(wfr[i], af[j],
                                                             acc[i][j], 0, 0, 0);
    }
    __syncthreads();
  }

  // epilogue: D[c][t], col = t -> coalesced stores
#pragma unroll
  for (int i = 0; i < 4; i++)
#pragma unroll
    for (int r = 0; r < 4; r++) {
      int crl = cw + i * 16 + lq * 4 + r;
      float bias = sB[crl];
#pragma unroll
      for (int j = 0; j < 4; j++) {
        int tcl = tw + j * 16 + lm;
        out[(size_t)b * 65536 + (size_t)(n0g + crl) * 256 + t0 + tcl] =
            acc[i][j][r] + bias;
      }
    }
}

// ---------------------------------------------------------------------------
extern "C" void kernel_launch(void* const* d_in, const int* in_sizes, int n_in,
                              void* d_out, int out_size, void* d_ws,
                              size_t ws_size, hipStream_t stream) {
  const float* x = (const float*)d_in[0];
  const float* w_qkv = (const float*)d_in[1];
  const float* b_qkv = (const float*)d_in[2];
  const float* w_proj = (const float*)d_in[3];
  const float* b_proj = (const float*)d_in[4];
  const float* mw1 = (const float*)d_in[5];
  const float* mb1 = (const float*)d_in[6];
  const float* mw2 = (const float*)d_in[7];
  const float* mb2 = (const float*)d_in[8];
  const float* tau = (const float*)d_in[9];
  float* out = (float*)d_out;

  const size_t NEEDED = (size_t)(TBL * NH + NH) * 4 + (size_t)65536 * 2 +
                        (size_t)256 * NH * Tt * HD * 2;
  if (ws_size < NEEDED) return;

  float* table = (float*)d_ws;
  float* tablemax = table + TBL * NH;
  f16* wpf = (f16*)(tablemax + NH);
  f16* attnH = wpf + 65536;

  // Stash f16 intermediates in d_out (64 MB fp32): xt = 33.5 MB, wqf = 384 KB.
  // proj_gemm fully overwrites d_out afterwards (stream-ordered).
  f16* xt = (f16*)d_out;
  f16* wqf = (f16*)d_out + (size_t)256 * 65536;

  stage0_kernel<<<4160, 256, 0, stream>>>(x, xt, mw1, mb1, mw2, mb2, w_proj,
                                          w_qkv, table, tablemax, wpf, wqf);
  fused_attn<<<256 * NH, 512, 0, stream>>>(xt, wqf, b_qkv, table, tablemax,
                                           tau, attnH);
  dim3 g3(512, 2);
  proj_gemm<<<g3, 256, 0, stream>>>(attnH, wpf, b_proj, out);
}

// Round 6
// 242.294 us; speedup vs baseline: 1.1571x; 1.0099x over previous
//
#include <hip/hip_runtime.h>
#include <math.h>

#define Cc 256
#define NH 8
#define HD 32
#define Tt 256
#define MH 256
#define TBL 961  // 31*31 distinct relative offsets

typedef _Float16 f16;
typedef f16 f16x4 __attribute__((ext_vector_type(4)));
typedef f16 f16x8 __attribute__((ext_vector_type(8)));
typedef float f32x4 __attribute__((ext_vector_type(4)));

// stride-32 f16 rows, 16B-chunk XOR swizzle, key=(row>>2)&3.
__device__ __forceinline__ f16x8 ld8(const f16* base, int row, int kc) {
  return *(const f16x8*)&base[row * 32 + ((kc ^ ((row >> 2) & 3)) << 3)];
}
__device__ __forceinline__ void st8(f16* base, int row, int kc, f16x8 v) {
  *(f16x8*)&base[row * 32 + ((kc ^ ((row >> 2) & 3)) << 3)] = v;
}
__device__ __forceinline__ int sidx(int row, int col) {
  return row * 32 + (((col >> 3) ^ ((row >> 2) & 3)) << 3) + (col & 7);
}
// Vt: [d=32][t=256] stride 256, full 3-bit XOR: chunk ^= (d&7).
__device__ __forceinline__ int vsidx(int d, int t) {
  return d * 256 + (((t >> 3) ^ (d & 7)) << 3) + (t & 7);
}
__device__ __forceinline__ f16x8 vld8(const f16* base, int d, int tch) {
  return *(const f16x8*)&base[d * 256 + ((tch ^ (d & 7)) << 3)];
}

// ---------------------------------------------------------------------------
// Kernel 1 (stage0 = merged prep+xpose).
// Blocks 0..4095: transpose+convert x [B][C][T] fp32 -> xt [B][T][C] f16.
//   Stores: 8 lanes x 16B per row -> 128B-contiguous segments.
// Blocks 4096..4103: bias-MLP table.  4104..4135: w_proj fp32->f16.
// 4136..4159: w_qkv gather.
// ---------------------------------------------------------------------------
__global__ __launch_bounds__(256) void stage0_kernel(
    const float* __restrict__ x, f16* __restrict__ xt,
    const float* __restrict__ mw1, const float* __restrict__ mb1,
    const float* __restrict__ mw2, const float* __restrict__ mb2,
    const float* __restrict__ w_proj, const float* __restrict__ w_qkv,
    float* __restrict__ table, float* __restrict__ tablemax,
    f16* __restrict__ wpf, f16* __restrict__ wqf) {
  __shared__ __align__(16) char smem0[9216];
  int tid = threadIdx.x;
  int blk = blockIdx.x;

  if (blk < 4096) {  // ---- xpose: 64x64 tile, float4 loads (G13)
    f16* tile = (f16*)smem0;  // [64][72] f16, 8-chunk XOR swizzle
    int b = blk >> 4, ti = (blk >> 2) & 3, tj = blk & 3;
    const float* xb = x + (size_t)b * 65536;
    int t4 = (tid & 15) * 4, cg = tid >> 4;
#pragma unroll
    for (int p = 0; p < 4; p++) {
      int cl = cg + p * 16;
      float4 v = *(const float4*)&xb[(size_t)(ti * 64 + cl) * 256 + tj * 64 + t4];
      const float* vp = (const float*)&v;
#pragma unroll
      for (int u = 0; u < 4; u++) {
        int tl = t4 + u;
        tile[tl * 72 + (((cl >> 3) ^ (tl & 7)) << 3) + (cl & 7)] = (f16)vp[u];
      }
    }
    __syncthreads();
    f16* xtb = xt + (size_t)b * 65536;
    int tr = tid >> 3, ck = tid & 7;  // 8 lanes cover one 128B row segment
#pragma unroll
    for (int u = 0; u < 2; u++) {
      int r = tr + u * 32;
      f16x8 v = *(const f16x8*)&tile[r * 72 + ((ck ^ (r & 7)) << 3)];
      *(f16x8*)&xtb[(size_t)(tj * 64 + r) * 256 + ti * 64 + ck * 8] = v;
    }
    return;
  }

  blk -= 4096;
  if (blk >= NH + 32) {  // ---- w_qkv gather+convert: 768 rows x 32 chunks
    int blk2 = blk - NH - 32;  // 0..23
#pragma unroll
    for (int pass = 0; pass < 4; pass++) {
      int chunkid = blk2 * 256 + tid + pass * 6144;
      int row = chunkid >> 5, ck = chunkid & 31;  // row in [0,768)
      int hh = row / 96, n = row % 96;
      int srow = ((n >> 5) << 8) + (hh << 5) + (n & 31);
      const float* wp = w_qkv + (size_t)srow * Cc + ck * 8;
      f16x8 v;
#pragma unroll
      for (int u = 0; u < 8; u++) v[u] = (f16)wp[u];
      *(f16x8*)&wqf[(size_t)row * Cc + ck * 8] = v;
    }
    return;
  }
  if (blk >= NH) {  // ---- w_proj convert
    int base = (blk - NH) * 2048 + tid * 8;
    f16x8 v;
#pragma unroll
    for (int u = 0; u < 8; u++) v[u] = (f16)w_proj[base + u];
    *(f16x8*)&wpf[base] = v;
    return;
  }
  // ---- bias-MLP table for head `blk` (float4-packed weights, 4-entry ILP)
  float4* s_w = (float4*)smem0;              // [MH] {w1a, w1b, b1, w2}
  float* red = (float*)(smem0 + 4096);       // [256]
  for (int i = tid; i < MH; i += 256) {
    float4 w;
    w.x = mw1[2 * i];
    w.y = mw1[2 * i + 1];
    w.z = mb1[i];
    w.w = mw2[blk * MH + i];
    s_w[i] = w;
  }
  __syncthreads();
  float b2 = mb2[blk];
  float d0v[4], d1v[4], ov[4];
#pragma unroll
  for (int j = 0; j < 4; j++) {
    int idx = tid + j * 256;
    int ii = idx < TBL ? idx : TBL - 1;
    float fdi = (float)(ii / 31 - 15);
    float fdj = (float)(ii % 31 - 15);
    d0v[j] = (fdi > 0.f ? 1.f : (fdi < 0.f ? -1.f : 0.f)) * log1pf(fabsf(fdi));
    d1v[j] = (fdj > 0.f ? 1.f : (fdj < 0.f ? -1.f : 0.f)) * log1pf(fabsf(fdj));
    ov[j] = b2;
  }
  for (int m = 0; m < MH; m++) {
    float4 w = s_w[m];
#pragma unroll
    for (int j = 0; j < 4; j++) {
      float hid = fmaxf(fmaf(d0v[j], w.x, fmaf(d1v[j], w.y, w.z)), 0.f);
      ov[j] = fmaf(hid, w.w, ov[j]);
    }
  }
  float lmax = -1e30f;
#pragma unroll
  for (int j = 0; j < 4; j++) {
    int idx = tid + j * 256;
    if (idx < TBL) {
      table[blk * TBL + idx] = ov[j];
      lmax = fmaxf(lmax, ov[j]);
    }
  }
  red[tid] = lmax;
  __syncthreads();
  for (int s = 128; s > 0; s >>= 1) {
    if (tid < s) red[tid] = fmaxf(red[tid], red[tid + s]);
    __syncthreads();
  }
  if (tid == 0) tablemax[blk] = red[0];
}

// ---------------------------------------------------------------------------
// Kernel 2: fused QKV + cosine-sim attention, swapped-operand phase 2.
// Block = (b,h), 512 thr = 8 waves.
// R6: chunked XCD swizzle.  R7: f16 xt/wqf staging (153->106).
// R8: swizzled normalize + setprio (106->92).  R9: ones-MFMA denominator.
// R10 FAILED: P overlay size bug -- per-wave P is 2304 B (1152 f16), so
// 8 waves = 18432 B, overran tbv2 (at 9216) and Ka (at 16656) -> NaN.
// R11 fix: e-SEQUENTIAL P.  Per-wave P buffer = 16 rows x 36 f16 = 1152 B
// (8 waves = 9216 B exactly).  e=0: write rows lm, lgkmcnt(0), read pf[0];
// then e=1 reuses the same rows.  Same-wave DS ops execute in order; asm
// "memory" clobber pins compiler order.  LDS total 49424 B -> 3 blocks/CU.
// Layout: [0,9216) P (ph2) | [9216,16656) tbv2 | [16656,33040) Wa/Ka |
//         [33040,49424) Vt.  Phase 1 Xa uses [0,16384).
// ---------------------------------------------------------------------------
__global__ __launch_bounds__(512, 4) void fused_attn(
    const f16* __restrict__ xt, const f16* __restrict__ wqf,
    const float* __restrict__ b_qkv, const float* __restrict__ table,
    const float* __restrict__ tablemax, const float* __restrict__ tau,
    f16* __restrict__ attnH) {
  __shared__ __align__(16) char smem[49424];
  f16* Qa = (f16*)smem;                      // ph1: Xa; ph2: P (per-wave)
  f16* Ka = (f16*)(smem + 16656);            // ph1: Wa in first 6 KB
  f16* Vt = (f16*)(smem + 33040);
  float2* tbv2 = (float2*)(smem + 9216);     // 31x30 float2 = 7440 B
  f16* Xa = (f16*)smem;
  f16* Wa = (f16*)(smem + 16656);

  int tid = threadIdx.x;
  int o = blockIdx.x;
  int bh = ((o & 7) << 8) | (o >> 3);  // chunked XCD swizzle (grid 2048 % 8 == 0)
  int b = bh >> 3, h = bh & 7;
  int wv = tid >> 6, ln = tid & 63, lq = ln >> 4, lm = ln & 15;

  const float LOG2E = 1.4426950408889634f;
  float rtau = 1.0f / fmaxf(tau[h], 0.01f);
  float tmaxh = tablemax[h];

  float bj[6];
#pragma unroll
  for (int nt = 0; nt < 6; nt++) {
    int n = nt * 16 + lm;
    int row = ((n >> 5) << 8) + (h << 5) + (n & 31);
    bj[nt] = b_qkv[row];
  }

  // ---- Phase 1: QKV GEMM, M=256 N=96 K=256, MFMA 16x16x32_f16
  const f16* xtb = xt + (size_t)b * 65536;
  const f16* wqh = wqf + (size_t)h * 24576;
  int xt_ = tid >> 1, xkc = (tid & 1) * 2;  // thread's X chunk pair
  int wn = tid >> 2, wck = tid & 3;         // thread's W chunk (tid<384)

  f32x4 acc[2][6] = {};
  f16x8 xv0, xv1, wvv;
  xv0 = *(const f16x8*)&xtb[xt_ * 256 + xkc * 8];
  xv1 = *(const f16x8*)&xtb[xt_ * 256 + xkc * 8 + 8];
  if (tid < 384) wvv = *(const f16x8*)&wqh[wn * 256 + wck * 8];

  for (int c0 = 0; c0 < Cc; c0 += 32) {
    st8(Xa, xt_, xkc, xv0);
    st8(Xa, xt_, xkc + 1, xv1);
    if (tid < 384) st8(Wa, wn, wck, wvv);
    __syncthreads();
    if (c0 + 32 < Cc) {  // prefetch next K-slice under the MFMAs
      xv0 = *(const f16x8*)&xtb[xt_ * 256 + c0 + 32 + xkc * 8];
      xv1 = *(const f16x8*)&xtb[xt_ * 256 + c0 + 32 + xkc * 8 + 8];
      if (tid < 384) wvv = *(const f16x8*)&wqh[wn * 256 + c0 + 32 + wck * 8];
    }
    f16x8 af[2], bf[6];
#pragma unroll
    for (int e = 0; e < 2; e++) af[e] = ld8(Xa, wv * 32 + e * 16 + lm, lq);
#pragma unroll
    for (int nt = 0; nt < 6; nt++) bf[nt] = ld8(Wa, nt * 16 + lm, lq);
#pragma unroll
    for (int e = 0; e < 2; e++)
#pragma unroll
      for (int nt = 0; nt < 6; nt++)
        acc[e][nt] = __builtin_amdgcn_mfma_f32_16x16x32_f16(af[e], bf[nt],
                                                            acc[e][nt], 0, 0, 0);
    __syncthreads();
  }

  // epilogue: + bias, scatter to Qa/Ka (t-major, scalar) and Vt (d-major f16x4)
#pragma unroll
  for (int e = 0; e < 2; e++) {
#pragma unroll
    for (int nt = 0; nt < 6; nt++) {
      int d = (nt & 1) * 16 + lm;
      if (nt < 4) {
#pragma unroll
        for (int r = 0; r < 4; r++) {
          int t = wv * 32 + e * 16 + lq * 4 + r;
          f16 v = (f16)(acc[e][nt][r] + bj[nt]);
          if (nt < 2) Qa[sidx(t, d)] = v;
          else        Ka[sidx(t, d)] = v;
        }
      } else {
        int t0 = wv * 32 + e * 16 + lq * 4;
        f16x4 pv;
#pragma unroll
        for (int r = 0; r < 4; r++) pv[r] = (f16)(acc[e][nt][r] + bj[nt]);
        *(f16x4*)&Vt[vsidx(d, t0)] = pv;
      }
    }
  }
  __syncthreads();

  // normalize Q,K rows in place (fold rtau*log2e into Q); swizzled chunks
  if (tid < 256) {
    int t = tid;
    float s = 0.f;
    f16x8 v[4];
#pragma unroll
    for (int ck = 0; ck < 4; ck++) {
      v[ck] = ld8(Qa, t, ck);
#pragma unroll
      for (int u = 0; u < 8; u++) { float f = (float)v[ck][u]; s = fmaf(f, f, s); }
    }
    float sc_ = rsqrtf(s) * rtau * LOG2E;
#pragma unroll
    for (int ck = 0; ck < 4; ck++) {
      f16x8 o2;
#pragma unroll
      for (int u = 0; u < 8; u++) o2[u] = (f16)((float)v[ck][u] * sc_);
      st8(Qa, t, ck, o2);
    }
  } else {
    int t = tid - 256;
    float s = 0.f;
    f16x8 v[4];
#pragma unroll
    for (int ck = 0; ck < 4; ck++) {
      v[ck] = ld8(Ka, t, ck);
#pragma unroll
      for (int u = 0; u < 8; u++) { float f = (float)v[ck][u]; s = fmaf(f, f, s); }
    }
    float sc_ = rsqrtf(s);
#pragma unroll
    for (int ck = 0; ck < 4; ck++) {
      f16x8 o2;
#pragma unroll
      for (int u = 0; u < 8; u++) o2[u] = (f16)((float)v[ck][u] * sc_);
      st8(Ka, t, ck, o2);
    }
  }
  __syncthreads();

  // hoist Q fragments (B-operand rows q = wv*32+e*16+lm)
  f16x8 qf[2];
#pragma unroll
  for (int e = 0; e < 2; e++) qf[e] = ld8(Qa, wv * 32 + e * 16 + lm, lq);
  __syncthreads();  // all waves done reading Qa before it becomes P/tbv2

  // fill tbv2 (log2-domain, pre-shifted) into the dead Q region.
  // entry (di, c-1), c in [1,30]: {T(c), T(c-1)}
  for (int idx = tid; idx < 31 * 30; idx += 512) {
    int di_ = idx / 30, c = idx - di_ * 30 + 1;
    float t0 = table[h * TBL + di_ * 31 + c];
    float t1 = table[h * TBL + di_ * 31 + c - 1];
    float2 v;
    v.x = (t0 - tmaxh - rtau * 1.0001f) * LOG2E;
    v.y = (t1 - tmaxh - rtau * 1.0001f) * LOG2E;
    tbv2[idx] = v;
  }
  __syncthreads();

  f16* Pme = Qa + wv * 576;    // 16 rows x stride 36 f16 = 1152 B per wave
  int c0l = lm - lq * 4 + 15;  // lane-constant dj base, in [3,30]
  f32x4 acco[2][2] = {};
  f32x4 acco_s[2] = {};        // ones-MFMA row sums (softmax denominator)
  f16x8 onev;
#pragma unroll
  for (int u = 0; u < 8; u++) onev[u] = (f16)1.0f;
  int dibase = wv * 2 + 15;

  // ---- Phase 2: S^T = mfma(K,Q) -> e-sequential P roundtrip -> PV.
  for (int n0 = 0; n0 < Tt; n0 += 32) {
    f16x8 kf[2];
#pragma unroll
    for (int nt = 0; nt < 2; nt++) kf[nt] = ld8(Ka, n0 + nt * 16 + lm, lq);
    f32x4 zero = {0.f, 0.f, 0.f, 0.f};
    f32x4 sc[2][2];
    __builtin_amdgcn_s_setprio(1);
#pragma unroll
    for (int e = 0; e < 2; e++)
#pragma unroll
      for (int nt = 0; nt < 2; nt++)
        sc[e][nt] = __builtin_amdgcn_mfma_f32_16x16x32_f16(kf[nt], qf[e], zero,
                                                           0, 0, 0);
    __builtin_amdgcn_s_setprio(0);
    f16x8 pf[2];
#pragma unroll
    for (int e = 0; e < 2; e++) {
#pragma unroll
      for (int nt = 0; nt < 2; nt++) {
        int di_ = dibase + e - (n0 >> 4) - nt;
        float2 b01 = tbv2[di_ * 30 + c0l - 1];  // {T(c0l), T(c0l-1)}
        float2 b23 = tbv2[di_ * 30 + c0l - 3];  // {T(c0l-2), T(c0l-3)}
        f16x4 pv;
        pv[0] = (f16)exp2f(sc[e][nt][0] + b01.x);
        pv[1] = (f16)exp2f(sc[e][nt][1] + b01.y);
        pv[2] = (f16)exp2f(sc[e][nt][2] + b23.x);
        pv[3] = (f16)exp2f(sc[e][nt][3] + b23.y);
        *(f16x4*)&Pme[lm * 36 + nt * 16 + lq * 4] = pv;
      }
      // same-wave DS ops are in-order; clobber pins compiler order so e=1's
      // writes can't hoist above e=0's reads.
      asm volatile("s_waitcnt lgkmcnt(0)" ::: "memory");
      f16x4 p0 = *(f16x4*)&Pme[lm * 36 + lq * 8];
      f16x4 p1 = *(f16x4*)&Pme[lm * 36 + lq * 8 + 4];
      pf[e] = __builtin_shufflevector(p0, p1, 0, 1, 2, 3, 4, 5, 6, 7);
    }
    f16x8 vf[2];
#pragma unroll
    for (int dt = 0; dt < 2; dt++)
      vf[dt] = vld8(Vt, dt * 16 + lm, (n0 >> 3) + lq);
    __builtin_amdgcn_s_setprio(1);
#pragma unroll
    for (int e = 0; e < 2; e++) {
#pragma unroll
      for (int dt = 0; dt < 2; dt++)
        acco[e][dt] = __builtin_amdgcn_mfma_f32_16x16x32_f16(pf[e], vf[dt],
                                                             acco[e][dt], 0, 0, 0);
      acco_s[e] = __builtin_amdgcn_mfma_f32_16x16x32_f16(pf[e], onev,
                                                         acco_s[e], 0, 0, 0);
    }
    __builtin_amdgcn_s_setprio(0);
  }

  // acco_s[e][r] = sum_n P[q][n] for exactly this thread's epilogue rows.
#pragma unroll
  for (int e = 0; e < 2; e++)
#pragma unroll
    for (int r = 0; r < 4; r++) {
      float rl = __builtin_amdgcn_rcpf(acco_s[e][r]);
      int q = wv * 32 + e * 16 + lq * 4 + r;
#pragma unroll
      for (int dt = 0; dt < 2; dt++) {
        int d = dt * 16 + lm;
        attnH[((size_t)b * Tt + q) * Cc + h * HD + d] =
            (f16)(acco[e][dt][r] * rl);
      }
    }
}

// ---------------------------------------------------------------------------
// Kernel 3: MFMA proj GEMM, coalesced staging.  A fp16 [B*T][256] x Wf fp16
// [256][256] -> out[b][c][t].  K-step 64 (128B row segments), stride-72 LDS,
// 37.4 KB -> 4 blocks/CU.
// ---------------------------------------------------------------------------
__global__ __launch_bounds__(256, 4) void proj_gemm(
    const f16* __restrict__ A, const f16* __restrict__ wf,
    const float* __restrict__ bp, float* __restrict__ out) {
  __shared__ __align__(16) f16 Af[128 * 72];   // 18432 B
  __shared__ __align__(16) f16 Wsh[128 * 72];  // 18432 B
  __shared__ float sB[128];
  int tid = threadIdx.x;
  int row0 = blockIdx.x * 128;
  int n0g = blockIdx.y * 128;
  int b = row0 >> 8, t0 = row0 & 255;
  int wv = tid >> 6, ln = tid & 63, lq = ln >> 4, lm = ln & 15;
  int cw = (wv & 1) * 64, tw = (wv >> 1) * 64;

  if (tid < 128) sB[tid] = bp[n0g + tid];

  f32x4 acc[4][4] = {};
  for (int k0 = 0; k0 < Cc; k0 += 64) {
#pragma unroll
    for (int p = 0; p < 4; p++) {
      int idx = p * 256 + tid;
      int row = idx >> 3, ch = idx & 7;
      f16x8 v = *(const f16x8*)&A[(size_t)(row0 + row) * Cc + k0 + ch * 8];
      *(f16x8*)&Af[row * 72 + ch * 8] = v;
    }
#pragma unroll
    for (int p = 0; p < 4; p++) {
      int idx = p * 256 + tid;
      int row = idx >> 3, ch = idx & 7;
      f16x8 v = *(const f16x8*)&wf[(size_t)(n0g + row) * Cc + k0 + ch * 8];
      *(f16x8*)&Wsh[row * 72 + ch * 8] = v;
    }
    __syncthreads();
#pragma unroll
    for (int kk = 0; kk < 2; kk++) {
      f16x8 wfr[4], af[4];
#pragma unroll
      for (int i = 0; i < 4; i++)
        wfr[i] = *(f16x8*)&Wsh[(cw + i * 16 + lm) * 72 + (kk * 4 + lq) * 8];
#pragma unroll
      for (int j = 0; j < 4; j++)
        af[j] = *(f16x8*)&Af[(tw + j * 16 + lm) * 72 + (kk * 4 + lq) * 8];
#pragma unroll
      for (int i = 0; i < 4; i++)
#pragma unroll
        for (int j = 0; j < 4; j++)
          acc[i][j] = __builtin_amdgcn_mfma_f32_16x16x32_f16(wfr[i], af[j],
                                                             acc[i][j], 0, 0, 0);
    }
    __syncthreads();
  }

  // epilogue: D[c][t], col = t -> coalesced stores
#pragma unroll
  for (int i = 0; i < 4; i++)
#pragma unroll
    for (int r = 0; r < 4; r++) {
      int crl = cw + i * 16 + lq * 4 + r;
      float bias = sB[crl];
#pragma unroll
      for (int j = 0; j < 4; j++) {
        int tcl = tw + j * 16 + lm;
        out[(size_t)b * 65536 + (size_t)(n0g + crl) * 256 + t0 + tcl] =
            acc[i][j][r] + bias;
      }
    }
}

// ---------------------------------------------------------------------------
extern "C" void kernel_launch(void* const* d_in, const int* in_sizes, int n_in,
                              void* d_out, int out_size, void* d_ws,
                              size_t ws_size, hipStream_t stream) {
  const float* x = (const float*)d_in[0];
  const float* w_qkv = (const float*)d_in[1];
  const float* b_qkv = (const float*)d_in[2];
  const float* w_proj = (const float*)d_in[3];
  const float* b_proj = (const float*)d_in[4];
  const float* mw1 = (const float*)d_in[5];
  const float* mb1 = (const float*)d_in[6];
  const float* mw2 = (const float*)d_in[7];
  const float* mb2 = (const float*)d_in[8];
  const float* tau = (const float*)d_in[9];
  float* out = (float*)d_out;

  const size_t NEEDED = (size_t)(TBL * NH + NH) * 4 + (size_t)65536 * 2 +
                        (size_t)256 * NH * Tt * HD * 2;
  if (ws_size < NEEDED) return;

  float* table = (float*)d_ws;
  float* tablemax = table + TBL * NH;
  f16* wpf = (f16*)(tablemax + NH);
  f16* attnH = wpf + 65536;

  // Stash f16 intermediates in d_out (64 MB fp32): xt = 33.5 MB, wqf = 384 KB.
  // proj_gemm fully overwrites d_out afterwards (stream-ordered).
  f16* xt = (f16*)d_out;
  f16* wqf = (f16*)d_out + (size_t)256 * 65536;

  stage0_kernel<<<4160, 256, 0, stream>>>(x, xt, mw1, mb1, mw2, mb2, w_proj,
                                          w_qkv, table, tablemax, wpf, wqf);
  fused_attn<<<256 * NH, 512, 0, stream>>>(xt, wqf, b_qkv, table, tablemax,
                                           tau, attnH);
  dim3 g3(512, 2);
  proj_gemm<<<g3, 256, 0, stream>>>(attnH, wpf, b_proj, out);
}